// Round 7
// baseline (551.824 us; speedup 1.0000x reference)
//
#include <hip/hip_runtime.h>
#include <math.h>

#define NTOK 4096
#define DEMB 1024
#define TSEQ 2048
#define QKVS 3072
#define QKN  2048
#define EDIM 2048
#define NEXP 8

typedef unsigned short u16;
typedef unsigned int u32;
typedef __bf16 bf16_t;
typedef __bf16 bf16x8 __attribute__((ext_vector_type(8)));
typedef __bf16 bf16x4 __attribute__((ext_vector_type(4)));
typedef float f32x4 __attribute__((ext_vector_type(4)));

__device__ __forceinline__ f32x4 mfma16(bf16x8 a, bf16x8 b, f32x4 c) {
    return __builtin_amdgcn_mfma_f32_16x16x32_bf16(a, b, c, 0, 0, 0);
}
__device__ __forceinline__ void gll16(const void* g, void* l) {
    __builtin_amdgcn_global_load_lds((const __attribute__((address_space(1))) u32*)g,
                                     (__attribute__((address_space(3))) u32*)l, 16, 0, 0);
}
__device__ __forceinline__ u16 f2bf(float x) {
    union { __bf16 h; u16 u; } c; c.h = (__bf16)x; return c.u;
}

// ---------------- rmsnorm fp32 -> split bf16 (hi, lo) ----------------
__global__ __launch_bounds__(256) void rmsnorm_split_k(const float* __restrict__ x,
                                                       bf16_t* __restrict__ hi,
                                                       bf16_t* __restrict__ lo) {
    const int row = blockIdx.x;
    const float4 v = ((const float4*)(x + (size_t)row * DEMB))[threadIdx.x];
    float ss = v.x*v.x + v.y*v.y + v.z*v.z + v.w*v.w;
    #pragma unroll
    for (int off = 32; off; off >>= 1) ss += __shfl_xor(ss, off);
    __shared__ float wsum[4];
    if ((threadIdx.x & 63) == 0) wsum[threadIdx.x >> 6] = ss;
    __syncthreads();
    const float r = rsqrtf((wsum[0]+wsum[1]+wsum[2]+wsum[3]) * (1.0f/DEMB) + 1e-5f);
    const float f[4] = {v.x*r, v.y*r, v.z*r, v.w*r};
    bf16x4 hv, lv;
    #pragma unroll
    for (int j = 0; j < 4; j++) {
        const __bf16 hb = (__bf16)f[j];
        hv[j] = hb;
        lv[j] = (__bf16)(f[j] - (float)hb);
    }
    ((bf16x4*)(hi + (size_t)row*DEMB))[threadIdx.x] = hv;
    ((bf16x4*)(lo + (size_t)row*DEMB))[threadIdx.x] = lv;
}

// ---------------- rmsnorm fp32 -> plain bf16 ----------------
__global__ __launch_bounds__(256) void rmsnorm_bf_k(const float* __restrict__ x,
                                                    bf16_t* __restrict__ y) {
    const int row = blockIdx.x;
    const float4 v = ((const float4*)(x + (size_t)row * DEMB))[threadIdx.x];
    float ss = v.x*v.x + v.y*v.y + v.z*v.z + v.w*v.w;
    #pragma unroll
    for (int off = 32; off; off >>= 1) ss += __shfl_xor(ss, off);
    __shared__ float wsum[4];
    if ((threadIdx.x & 63) == 0) wsum[threadIdx.x >> 6] = ss;
    __syncthreads();
    const float r = rsqrtf((wsum[0]+wsum[1]+wsum[2]+wsum[3]) * (1.0f/DEMB) + 1e-5f);
    bf16x4 o;
    o[0] = (__bf16)(v.x*r); o[1] = (__bf16)(v.y*r);
    o[2] = (__bf16)(v.z*r); o[3] = (__bf16)(v.w*r);
    ((bf16x4*)(y + (size_t)row*DEMB))[threadIdx.x] = o;
}

// ---------------- weight transpose fp32 [K][M] -> split bf16 [M][K] ----------------
__global__ __launch_bounds__(256) void transp_split_k(const float* __restrict__ w,
                                                      bf16_t* __restrict__ wth,
                                                      bf16_t* __restrict__ wtl,
                                                      int K, int M) {
    __shared__ float t[32][33];
    const int m0 = blockIdx.x*32, k0 = blockIdx.y*32;
    const int tx = threadIdx.x & 31, ty = threadIdx.x >> 5;
    #pragma unroll
    for (int i = 0; i < 32; i += 8) t[ty+i][tx] = w[(size_t)(k0+ty+i)*M + m0+tx];
    __syncthreads();
    #pragma unroll
    for (int i = 0; i < 32; i += 8) {
        const float f = t[tx][ty+i];
        const __bf16 hb = (__bf16)f;
        wth[(size_t)(m0+ty+i)*K + k0+tx] = hb;
        wtl[(size_t)(m0+ty+i)*K + k0+tx] = (__bf16)(f - (float)hb);
    }
}

// ---------------- weight transpose fp32 [K][M] -> plain bf16 [M][K] (per expert) ------
__global__ __launch_bounds__(256) void transp_k(const float* __restrict__ w,
                                                bf16_t* __restrict__ wt,
                                                int K, int M) {
    __shared__ float t[32][33];
    const size_t eo = (size_t)blockIdx.z * K * M;
    w += eo; wt += eo;
    const int m0 = blockIdx.x*32, k0 = blockIdx.y*32;
    const int tx = threadIdx.x & 31, ty = threadIdx.x >> 5;
    #pragma unroll
    for (int i = 0; i < 32; i += 8) t[ty+i][tx] = w[(size_t)(k0+ty+i)*M + m0+tx];
    __syncthreads();
    #pragma unroll
    for (int i = 0; i < 32; i += 8) wt[(size_t)(m0+ty+i)*K + k0+tx] = (__bf16)t[tx][ty+i];
}

// ---------------- split-bf16 GEMM: C = (Ah+Al)(Bh+Bl)^T, 3 MFMA products ----
// EPI 1: fp32 store = res + acc
// EPI 3: QKV epilogue -> Q (x0.125) and K split into qk [tok][2048]; V split into V^T [bh*64+d][t]
template<int EPI>
__global__ __launch_bounds__(256) void gemm_split(const bf16_t* __restrict__ Ah,
                                                  const bf16_t* __restrict__ Al,
                                                  const bf16_t* __restrict__ Bh,
                                                  const bf16_t* __restrict__ Bl,
                                                  const float* __restrict__ res,
                                                  float* __restrict__ C,
                                                  bf16_t* __restrict__ qkh,
                                                  bf16_t* __restrict__ qkl,
                                                  bf16_t* __restrict__ vth,
                                                  bf16_t* __restrict__ vtl,
                                                  int N, int K) {
    __shared__ u16 AsH[128*32];
    __shared__ u16 AsL[128*32];
    __shared__ u16 BsH[128*32];
    __shared__ u16 BsL[128*32];
    const int tid = threadIdx.x;
    const int lane = tid & 63, w = tid >> 6;
    const int lr = lane & 15, lg = lane >> 4;
    const int wm = w >> 1, wn = w & 1;
    const int m0 = blockIdx.y * 128, n0 = blockIdx.x * 128;
    const int rs = tid >> 2, ks = (tid & 3) * 8;
    const size_t arow0 = (size_t)(m0 + rs) * K + ks;
    const size_t arow1 = (size_t)(m0 + 64 + rs) * K + ks;
    const size_t brow0 = (size_t)(n0 + rs) * K + ks;
    const size_t brow1 = (size_t)(n0 + 64 + rs) * K + ks;
    char* lah = (char*)AsH + tid*16;
    char* lal = (char*)AsL + tid*16;
    char* lbh = (char*)BsH + tid*16;
    char* lbl = (char*)BsL + tid*16;
    f32x4 acc[4][4] = {};
    for (int k0 = 0; k0 < K; k0 += 32) {
        __syncthreads();
        gll16(Ah + arow0 + k0, lah); gll16(Ah + arow1 + k0, lah + 4096);
        gll16(Al + arow0 + k0, lal); gll16(Al + arow1 + k0, lal + 4096);
        gll16(Bh + brow0 + k0, lbh); gll16(Bh + brow1 + k0, lbh + 4096);
        gll16(Bl + brow0 + k0, lbl); gll16(Bl + brow1 + k0, lbl + 4096);
        __syncthreads();
        bf16x8 ah[4], al[4], bh[4], bl[4];
        #pragma unroll
        for (int i = 0; i < 4; i++) {
            const int ao = (wm*64 + i*16 + lr)*32 + lg*8;
            const int bo = (wn*64 + i*16 + lr)*32 + lg*8;
            ah[i] = *(const bf16x8*)&AsH[ao];
            al[i] = *(const bf16x8*)&AsL[ao];
            bh[i] = *(const bf16x8*)&BsH[bo];
            bl[i] = *(const bf16x8*)&BsL[bo];
        }
        #pragma unroll
        for (int i = 0; i < 4; i++)
            #pragma unroll
            for (int j = 0; j < 4; j++) {
                acc[i][j] = mfma16(ah[i], bh[j], acc[i][j]);
                acc[i][j] = mfma16(ah[i], bl[j], acc[i][j]);
                acc[i][j] = mfma16(al[i], bh[j], acc[i][j]);
            }
    }
    #pragma unroll
    for (int i = 0; i < 4; i++) {
        #pragma unroll
        for (int j = 0; j < 4; j++) {
            const int row = m0 + wm*64 + i*16 + lg*4;
            const int col = n0 + wn*64 + j*16 + lr;
            const f32x4 v = acc[i][j];
            if (EPI == 1) {
                #pragma unroll
                for (int r = 0; r < 4; r++) {
                    const size_t o = (size_t)(row + r) * N + col;
                    C[o] = res[o] + v[r];
                }
            } else {
                if (col < QKN) {   // Q (scaled) or K
                    const float sc = (col < DEMB) ? 0.125f : 1.0f;
                    #pragma unroll
                    for (int r = 0; r < 4; r++) {
                        const size_t o = (size_t)(row + r) * QKN + col;
                        const float f = v[r] * sc;
                        const __bf16 hb = (__bf16)f;
                        qkh[o] = hb;
                        qkl[o] = (__bf16)(f - (float)hb);
                    }
                } else {           // V -> V^T [ (b*16+h)*64 + d ][ t ]
                    const int d = col - QKN;
                    const int hh = d >> 6, dd = d & 63;
                    const int bb = row >> 11, t = row & 2047;
                    const size_t base = ((size_t)(bb*16 + hh)*64 + dd) * TSEQ + t;
                    #pragma unroll
                    for (int r = 0; r < 4; r++) {
                        const float f = v[r];
                        const __bf16 hb = (__bf16)f;
                        vth[base + r] = hb;
                        vtl[base + r] = (__bf16)(f - (float)hb);
                    }
                }
            }
        }
    }
}

// ---------------- grouped per-expert bf16 GEMM (EPI 2: relu^2; EPI 3: plain) ----------
template<int EPI, int GATHER>
__global__ __launch_bounds__(256) void gemm_moe(const bf16_t* __restrict__ A,
                                                const bf16_t* __restrict__ Ball,
                                                bf16_t* __restrict__ C,
                                                const int* __restrict__ rowmap,
                                                const int* __restrict__ counts,
                                                const int* __restrict__ offs,
                                                int N, int K) {
    const int e = blockIdx.z;
    const int cnt = counts[e];
    if ((int)blockIdx.y * 128 >= cnt) return;
    const int base = offs[e];
    const bf16_t* Bt = Ball + (size_t)e * N * K;
    __shared__ u16 As[128*32];
    __shared__ u16 Bs[128*32];
    const int tid = threadIdx.x;
    const int lane = tid & 63, w = tid >> 6;
    const int lr = lane & 15, lg = lane >> 4;
    const int wm = w >> 1, wn = w & 1;
    const int m0 = blockIdx.y * 128, n0 = blockIdx.x * 128;
    const int rs = tid >> 2, ks = (tid & 3) * 8;
    const int l0 = min(m0 + rs, cnt - 1), l1 = min(m0 + 64 + rs, cnt - 1);
    const size_t r0 = GATHER ? (size_t)rowmap[base + l0] : (size_t)(base + l0);
    const size_t r1 = GATHER ? (size_t)rowmap[base + l1] : (size_t)(base + l1);
    const bf16_t* ga0 = A  + r0 * K + ks;
    const bf16_t* ga1 = A  + r1 * K + ks;
    const bf16_t* gb0 = Bt + (size_t)(n0 + rs)      * K + ks;
    const bf16_t* gb1 = Bt + (size_t)(n0 + 64 + rs) * K + ks;
    char* la0 = (char*)As + tid*16; char* la1 = la0 + 4096;
    char* lb0 = (char*)Bs + tid*16; char* lb1 = lb0 + 4096;
    f32x4 acc[4][4] = {};
    for (int k0 = 0; k0 < K; k0 += 32) {
        __syncthreads();
        gll16(ga0 + k0, la0); gll16(ga1 + k0, la1);
        gll16(gb0 + k0, lb0); gll16(gb1 + k0, lb1);
        __syncthreads();
        bf16x8 af[4], bfr[4];
        #pragma unroll
        for (int i = 0; i < 4; i++) {
            af[i]  = *(const bf16x8*)&As[(wm*64 + i*16 + lr)*32 + lg*8];
            bfr[i] = *(const bf16x8*)&Bs[(wn*64 + i*16 + lr)*32 + lg*8];
        }
        #pragma unroll
        for (int i = 0; i < 4; i++)
            #pragma unroll
            for (int j = 0; j < 4; j++)
                acc[i][j] = mfma16(af[i], bfr[j], acc[i][j]);
    }
    #pragma unroll
    for (int i = 0; i < 4; i++) {
        #pragma unroll
        for (int j = 0; j < 4; j++) {
            const int rowl = m0 + wm*64 + i*16 + lg*4;
            const int col  = n0 + wn*64 + j*16 + lr;
            const f32x4 v = acc[i][j];
            #pragma unroll
            for (int r = 0; r < 4; r++) {
                if (rowl + r < cnt) {
                    float xv = v[r];
                    if (EPI == 2) { xv = fmaxf(xv, 0.f); xv = xv * xv; }
                    C[(size_t)(base + rowl + r) * N + col] = (__bf16)xv;
                }
            }
        }
    }
}

// ---------------- split-bf16 MFMA flash attention, causal, balanced pairs ----------------
// grid (16,16,2): block handles q-tiles qa=bx and qb=31-bx (64 rows each) in ONE kv sweep.
// 4 waves x 16 q-rows per tile. K from qk buffer; V^T pre-transposed in global.
__global__ __launch_bounds__(256) void attn_mfma(const bf16_t* __restrict__ qkh,
                                                 const bf16_t* __restrict__ qkl,
                                                 const bf16_t* __restrict__ vth,
                                                 const bf16_t* __restrict__ vtl,
                                                 bf16_t* __restrict__ aoh,
                                                 bf16_t* __restrict__ aol) {
    __shared__ u16 KsH[64*64];   // [kv][d], chunk-swizzled c^=kv&7
    __shared__ u16 KsL[64*64];
    __shared__ u16 VtH[64*64];   // [d][kv], chunk-swizzled c^=d&7 (src pre-swizzled)
    __shared__ u16 VtL[64*64];
    __shared__ u16 P_H[4*16*72]; // per-wave P / output bounce
    __shared__ u16 P_L[4*16*72];
    const int tid = threadIdx.x, lane = tid & 63, wv = tid >> 6;
    const int lr = lane & 15, lg = lane >> 4;
    const int h = blockIdx.y, b = blockIdx.z;
    const int qa = blockIdx.x, qb = 31 - qa;
    u16* plwH = P_H + wv * 16 * 72;
    u16* plwL = P_L + wv * 16 * 72;
    const int wq0A = qa*64 + wv*16;
    const int wq0B = qb*64 + wv*16;

    bf16x8 qAh[2], qAl[2], qBh[2], qBl[2];
    #pragma unroll
    for (int kf = 0; kf < 2; kf++) {
        const size_t qoA = (size_t)(b*TSEQ + wq0A + lr)*QKN + h*64 + kf*32 + lg*8;
        const size_t qoB = (size_t)(b*TSEQ + wq0B + lr)*QKN + h*64 + kf*32 + lg*8;
        qAh[kf] = *(const bf16x8*)(qkh + qoA);
        qAl[kf] = *(const bf16x8*)(qkl + qoA);
        qBh[kf] = *(const bf16x8*)(qkh + qoB);
        qBl[kf] = *(const bf16x8*)(qkl + qoB);
    }

    f32x4 ofA[4] = {}, ofB[4] = {};
    float mA = -1e30f, lA = 0.f, mB = -1e30f, lB = 0.f;

    const int skv = tid >> 3;                 // 0..31
    const int pst = tid & 7;
    const int chs = pst ^ (skv & 7);          // swizzled source chunk (K and V^T alike)
    const int bh = b*16 + h;
    const bf16_t* kh = qkh + 1024;
    const bf16_t* kl = qkl + 1024;
    const size_t vrow0 = (size_t)(bh*64 + skv)      * TSEQ;
    const size_t vrow1 = (size_t)(bh*64 + skv + 32) * TSEQ;

    auto step = [&](f32x4 (&of)[4], float& mrun, float& lrun,
                    const bf16x8 (&qfh)[2], const bf16x8 (&qfl)[2],
                    const int wq0, const bool diag, const int kvb) {
        f32x4 sf[4] = {};
        #pragma unroll
        for (int kf = 0; kf < 2; kf++)
            #pragma unroll
            for (int f = 0; f < 4; f++) {
                const int idx = (f*16 + lr)*64 + ((kf*32 + lg*8) ^ ((lr & 7) << 3));
                const bf16x8 ah = *(const bf16x8*)&KsH[idx];
                const bf16x8 al = *(const bf16x8*)&KsL[idx];
                sf[f] = mfma16(ah, qfh[kf], sf[f]);
                sf[f] = mfma16(ah, qfl[kf], sf[f]);
                sf[f] = mfma16(al, qfh[kf], sf[f]);
            }
        if (diag) {
            #pragma unroll
            for (int f = 0; f < 4; f++)
                #pragma unroll
                for (int r = 0; r < 4; r++)
                    if (kvb + f*16 + lg*4 + r > wq0 + lr) sf[f][r] = -1e30f;
        }
        float tm = -1e30f;
        #pragma unroll
        for (int f = 0; f < 4; f++)
            tm = fmaxf(tm, fmaxf(fmaxf(sf[f][0], sf[f][1]), fmaxf(sf[f][2], sf[f][3])));
        tm = fmaxf(tm, __shfl_xor(tm, 16));
        tm = fmaxf(tm, __shfl_xor(tm, 32));
        const float mnew = fmaxf(mrun, tm);
        const float fac = __expf(mrun - mnew);
        mrun = mnew;
        float ps = 0.f;
        #pragma unroll
        for (int f = 0; f < 4; f++) {
            float p[4];
            #pragma unroll
            for (int r = 0; r < 4; r++) { p[r] = __expf(sf[f][r] - mnew); ps += p[r]; }
            u16 hb4[4], lb4[4];
            #pragma unroll
            for (int r = 0; r < 4; r++) {
                const __bf16 hb = (__bf16)p[r];
                hb4[r] = f2bf(p[r]);
                lb4[r] = f2bf(p[r] - (float)hb);
            }
            u32* pwh = (u32*)&plwH[lr*72 + f*16 + lg*4];
            u32* pwl = (u32*)&plwL[lr*72 + f*16 + lg*4];
            pwh[0] = (u32)hb4[0] | ((u32)hb4[1] << 16);
            pwh[1] = (u32)hb4[2] | ((u32)hb4[3] << 16);
            pwl[0] = (u32)lb4[0] | ((u32)lb4[1] << 16);
            pwl[1] = (u32)lb4[2] | ((u32)lb4[3] << 16);
        }
        ps += __shfl_xor(ps, 16);
        ps += __shfl_xor(ps, 32);
        lrun = lrun*fac + ps;
        #pragma unroll
        for (int f2 = 0; f2 < 4; f2++)
            #pragma unroll
            for (int r = 0; r < 4; r++) of[f2][r] *= fac;
        #pragma unroll
        for (int hf = 0; hf < 2; hf++) {
            const bf16x8 pbh = *(const bf16x8*)&plwH[lr*72 + hf*32 + lg*8];
            const bf16x8 pbl = *(const bf16x8*)&plwL[lr*72 + hf*32 + lg*8];
            #pragma unroll
            for (int f2 = 0; f2 < 4; f2++) {
                const int vidx = (f2*16 + lr)*64 + (((hf*4 + lg) ^ (lr & 7)) << 3);
                const bf16x8 vah = *(const bf16x8*)&VtH[vidx];
                const bf16x8 val = *(const bf16x8*)&VtL[vidx];
                of[f2] = mfma16(vah, pbh, of[f2]);
                of[f2] = mfma16(vah, pbl, of[f2]);
                of[f2] = mfma16(val, pbh, of[f2]);
            }
        }
    };

    for (int kt = 0; kt <= qb; kt++) {
        __syncthreads();
        const size_t krow = (size_t)(b*TSEQ + kt*64 + skv)*QKN + h*64;
        gll16(kh + krow + chs*8,                     (char*)KsH + tid*16);
        gll16(kh + krow + (size_t)32*QKN + chs*8,    (char*)KsH + 4096 + tid*16);
        gll16(kl + krow + chs*8,                     (char*)KsL + tid*16);
        gll16(kl + krow + (size_t)32*QKN + chs*8,    (char*)KsL + 4096 + tid*16);
        gll16(vth + vrow0 + kt*64 + chs*8,           (char*)VtH + tid*16);
        gll16(vth + vrow1 + kt*64 + chs*8,           (char*)VtH + 4096 + tid*16);
        gll16(vtl + vrow0 + kt*64 + chs*8,           (char*)VtL + tid*16);
        gll16(vtl + vrow1 + kt*64 + chs*8,           (char*)VtL + 4096 + tid*16);
        __syncthreads();
        if (kt <= qa) step(ofA, mA, lA, qAh, qAl, wq0A, kt == qa, kt*64);
        step(ofB, mB, lB, qBh, qBl, wq0B, kt == qb, kt*64);
    }

    // epilogue per tile: normalize, split, bounce through per-wave LDS, coalesced store
    const float invA = 1.f / lA, invB = 1.f / lB;
    #pragma unroll
    for (int f2 = 0; f2 < 4; f2++) {
        u16 hb4[4], lb4[4];
        #pragma unroll
        for (int r = 0; r < 4; r++) {
            const float f = ofA[f2][r] * invA;
            const __bf16 hb = (__bf16)f;
            hb4[r] = f2bf(f);
            lb4[r] = f2bf(f - (float)hb);
        }
        u32* pwh = (u32*)&plwH[lr*72 + f2*16 + lg*4];
        u32* pwl = (u32*)&plwL[lr*72 + f2*16 + lg*4];
        pwh[0] = (u32)hb4[0] | ((u32)hb4[1] << 16);
        pwh[1] = (u32)hb4[2] | ((u32)hb4[3] << 16);
        pwl[0] = (u32)lb4[0] | ((u32)lb4[1] << 16);
        pwl[1] = (u32)lb4[2] | ((u32)lb4[3] << 16);
    }
    asm volatile("s_waitcnt lgkmcnt(0)" ::: "memory");
    __builtin_amdgcn_sched_barrier(0);
    #pragma unroll
    for (int pass = 0; pass < 2; pass++) {
        const int qlr = pass*8 + (lane >> 3);
        const int ch = (lane & 7) * 8;
        const bf16x8 oh = *(const bf16x8*)&plwH[qlr*72 + ch];
        const bf16x8 ol = *(const bf16x8*)&plwL[qlr*72 + ch];
        const size_t go = (size_t)(b*TSEQ + wq0A + qlr) * DEMB + h*64 + ch;
        *(bf16x8*)(aoh + go) = oh;
        *(bf16x8*)(aol + go) = ol;
    }
    asm volatile("s_waitcnt lgkmcnt(0)" ::: "memory");
    __builtin_amdgcn_sched_barrier(0);
    #pragma unroll
    for (int f2 = 0; f2 < 4; f2++) {
        u16 hb4[4], lb4[4];
        #pragma unroll
        for (int r = 0; r < 4; r++) {
            const float f = ofB[f2][r] * invB;
            const __bf16 hb = (__bf16)f;
            hb4[r] = f2bf(f);
            lb4[r] = f2bf(f - (float)hb);
        }
        u32* pwh = (u32*)&plwH[lr*72 + f2*16 + lg*4];
        u32* pwl = (u32*)&plwL[lr*72 + f2*16 + lg*4];
        pwh[0] = (u32)hb4[0] | ((u32)hb4[1] << 16);
        pwh[1] = (u32)hb4[2] | ((u32)hb4[3] << 16);
        pwl[0] = (u32)lb4[0] | ((u32)lb4[1] << 16);
        pwl[1] = (u32)lb4[2] | ((u32)lb4[3] << 16);
    }
    asm volatile("s_waitcnt lgkmcnt(0)" ::: "memory");
    __builtin_amdgcn_sched_barrier(0);
    #pragma unroll
    for (int pass = 0; pass < 2; pass++) {
        const int qlr = pass*8 + (lane >> 3);
        const int ch = (lane & 7) * 8;
        const bf16x8 oh = *(const bf16x8*)&plwH[qlr*72 + ch];
        const bf16x8 ol = *(const bf16x8*)&plwL[qlr*72 + ch];
        const size_t go = (size_t)(b*TSEQ + wq0B + qlr) * DEMB + h*64 + ch;
        *(bf16x8*)(aoh + go) = oh;
        *(bf16x8*)(aol + go) = ol;
    }
}

// ---------------- MoE routing (fp32, rmsnorm folded in) ----------------
__global__ void zero8(int* c) { if (threadIdx.x < NEXP) c[threadIdx.x] = 0; }

__global__ __launch_bounds__(256) void router_k(const float* __restrict__ xout,
                                                const float* __restrict__ rw,
                                                int* __restrict__ idx,
                                                float* __restrict__ wts,
                                                int* __restrict__ pos,
                                                int* __restrict__ counts) {
    const int tok = blockIdx.x * 4 + (threadIdx.x >> 6);
    const int lane = threadIdx.x & 63;
    const float* xr = xout + (size_t)tok * DEMB;
    float ss = 0.f;
    float acc[NEXP];
    #pragma unroll
    for (int e = 0; e < NEXP; e++) acc[e] = 0.f;
    for (int kk = lane; kk < DEMB; kk += 64) {
        const float xv = xr[kk];
        ss += xv * xv;
        #pragma unroll
        for (int e = 0; e < NEXP; e++) acc[e] += xv * rw[kk*NEXP + e];
    }
    #pragma unroll
    for (int off = 32; off; off >>= 1) ss += __shfl_xor(ss, off);
    #pragma unroll
    for (int e = 0; e < NEXP; e++) {
        #pragma unroll
        for (int off = 32; off; off >>= 1) acc[e] += __shfl_xor(acc[e], off);
    }
    if (lane == 0) {
        const float r = rsqrtf(ss * (1.0f/DEMB) + 1e-5f);
        float v[NEXP];
        #pragma unroll
        for (int e = 0; e < NEXP; e++) v[e] = acc[e] * r;
        int b0 = 0; float v0 = v[0];
        #pragma unroll
        for (int e = 1; e < NEXP; e++) if (v[e] > v0) { v0 = v[e]; b0 = e; }
        int b1 = -1; float v1 = -1e30f;
        #pragma unroll
        for (int e = 0; e < NEXP; e++) if (e != b0 && v[e] > v1) { v1 = v[e]; b1 = e; }
        const float w0 = 1.f / (1.f + __expf(v1 - v0));
        idx[tok*2+0] = b0; idx[tok*2+1] = b1;
        wts[tok*2+0] = w0; wts[tok*2+1] = 1.f - w0;
        pos[tok*2+0] = atomicAdd(&counts[b0], 1);
        pos[tok*2+1] = atomicAdd(&counts[b1], 1);
    }
}

__global__ void offsets_k(const int* __restrict__ counts, int* __restrict__ offs) {
    if (threadIdx.x == 0) {
        int s = 0;
        for (int e = 0; e < NEXP; e++) { offs[e] = s; s += counts[e]; }
    }
}

__global__ __launch_bounds__(256) void buildmap_k(const int* __restrict__ idx,
                                                  const int* __restrict__ pos,
                                                  const int* __restrict__ offs,
                                                  int* __restrict__ rowmap,
                                                  int* __restrict__ rowpos) {
    const int n = blockIdx.x * 256 + threadIdx.x;
    #pragma unroll
    for (int s = 0; s < 2; s++) {
        const int e = idx[n*2+s];
        const int r = offs[e] + pos[n*2+s];
        rowmap[r] = n;
        rowpos[n*2+s] = r;
    }
}

__global__ __launch_bounds__(256) void combine_k(const bf16_t* __restrict__ oe,
                                                 const int* __restrict__ rowpos,
                                                 const float* __restrict__ wts,
                                                 float* __restrict__ out) {
    const int n = blockIdx.x;
    const int r0 = rowpos[n*2+0], r1 = rowpos[n*2+1];
    const float w0 = wts[n*2+0], w1 = wts[n*2+1];
    const int c = threadIdx.x * 4;
    const bf16x4 a  = *(const bf16x4*)(oe + (size_t)r0*DEMB + c);
    const bf16x4 b4 = *(const bf16x4*)(oe + (size_t)r1*DEMB + c);
    float4* op = (float4*)(out + (size_t)n*DEMB + c);
    float4 o = *op;
    o.x += w0*(float)a[0] + w1*(float)b4[0];
    o.y += w0*(float)a[1] + w1*(float)b4[1];
    o.z += w0*(float)a[2] + w1*(float)b4[2];
    o.w += w0*(float)a[3] + w1*(float)b4[3];
    *op = o;
}

extern "C" void kernel_launch(void* const* d_in, const int* in_sizes, int n_in,
                              void* d_out, int out_size, void* d_ws, size_t ws_size,
                              hipStream_t stream) {
    (void)in_sizes; (void)n_in; (void)out_size; (void)ws_size;
    const float* x   = (const float*)d_in[0];
    const float* wq  = (const float*)d_in[1];
    const float* wk  = (const float*)d_in[2];
    const float* wv  = (const float*)d_in[3];
    const float* wo  = (const float*)d_in[4];
    const float* rw  = (const float*)d_in[5];
    const float* fc1 = (const float*)d_in[6];
    const float* fc2 = (const float*)d_in[7];
    float* out = (float*)d_out;
    char* ws = (char*)d_ws;
    const size_t MB = 1024*1024;

    // region map (MB), phase-overlaid:
    //  0-16 : wqkv_h(6) wqkv_l(6) wo_h(2) wo_l(2) [prep->WO]  -> oe(16) [moe2->combine]
    // 16-64 : qk_h(16)@16 qk_l(16)@32 vt_h(8)@48 vt_l(8)@56 [QKV->attn/WO]
    //         -> fc1_t(32)@16, fc2_t(32)@48 [post-WO -> moe]
    // 64-80 : h_hi(8) h_lo(8) [rms1->QKV]  -> ao_h(8) ao_l(8) [attn->WO]
    // 80-88 : h bf16 (rms2 out)  [->moe1]
    // 88-120: h1 bf16 (32)       [moe1->moe2]
    // 120+  : meta
    bf16_t* wqkv_h = (bf16_t*)(ws);
    bf16_t* wqkv_l = (bf16_t*)(ws + 6*MB);
    bf16_t* wo_h   = (bf16_t*)(ws + 12*MB);
    bf16_t* wo_l   = (bf16_t*)(ws + 14*MB);
    bf16_t* qk_h   = (bf16_t*)(ws + 16*MB);
    bf16_t* qk_l   = (bf16_t*)(ws + 32*MB);
    bf16_t* vt_h   = (bf16_t*)(ws + 48*MB);
    bf16_t* vt_l   = (bf16_t*)(ws + 56*MB);
    bf16_t* fc1_t  = (bf16_t*)(ws + 16*MB);
    bf16_t* fc2_t  = (bf16_t*)(ws + 48*MB);
    bf16_t* h_hi   = (bf16_t*)(ws + 64*MB);
    bf16_t* h_lo   = (bf16_t*)(ws + 72*MB);
    bf16_t* ao_h   = (bf16_t*)(ws + 64*MB);
    bf16_t* ao_l   = (bf16_t*)(ws + 72*MB);
    bf16_t* h      = (bf16_t*)(ws + 80*MB);
    bf16_t* h1     = (bf16_t*)(ws + 88*MB);
    bf16_t* oe     = (bf16_t*)(ws);
    char* meta = ws + 120*MB;
    int*   idx    = (int*)(meta);
    int*   pos    = (int*)(meta + 64*1024);
    int*   rowmap = (int*)(meta + 128*1024);
    int*   rowpos = (int*)(meta + 192*1024);
    float* wts    = (float*)(meta + 256*1024);
    int*   counts = (int*)(meta + 320*1024);
    int*   offs   = (int*)(meta + 320*1024 + 256);

    const dim3 blk(256);

    // ---- attention path ----
    transp_split_k<<<dim3(32,32), blk, 0, stream>>>(wq, wqkv_h,               wqkv_l,               1024, 1024);
    transp_split_k<<<dim3(32,32), blk, 0, stream>>>(wk, wqkv_h + 1024*1024,   wqkv_l + 1024*1024,   1024, 1024);
    transp_split_k<<<dim3(32,32), blk, 0, stream>>>(wv, wqkv_h + 2*1024*1024, wqkv_l + 2*1024*1024, 1024, 1024);
    transp_split_k<<<dim3(32,32), blk, 0, stream>>>(wo, wo_h,                 wo_l,                 1024, 1024);
    rmsnorm_split_k<<<NTOK, blk, 0, stream>>>(x, h_hi, h_lo);
    gemm_split<3><<<dim3(QKVS/128, NTOK/128), blk, 0, stream>>>(
        h_hi, h_lo, wqkv_h, wqkv_l, nullptr, nullptr, qk_h, qk_l, vt_h, vt_l, QKVS, 1024);
    attn_mfma<<<dim3(16, 16, 2), blk, 0, stream>>>(qk_h, qk_l, vt_h, vt_l, ao_h, ao_l);
    gemm_split<1><<<dim3(DEMB/128, NTOK/128), blk, 0, stream>>>(
        ao_h, ao_l, wo_h, wo_l, x, out, nullptr, nullptr, nullptr, nullptr, DEMB, 1024);

    // ---- MoE path (fp32 router, bf16 experts) ----
    transp_k<<<dim3(64,32,8), blk, 0, stream>>>(fc1, fc1_t, 1024, 2048);
    transp_k<<<dim3(32,64,8), blk, 0, stream>>>(fc2, fc2_t, 2048, 1024);
    rmsnorm_bf_k<<<NTOK, blk, 0, stream>>>(out, h);
    zero8<<<1, 64, 0, stream>>>(counts);
    router_k<<<NTOK/4, blk, 0, stream>>>(out, rw, idx, wts, pos, counts);
    offsets_k<<<1, 64, 0, stream>>>(counts, offs);
    buildmap_k<<<NTOK/256, blk, 0, stream>>>(idx, pos, offs, rowmap, rowpos);
    gemm_moe<2,1><<<dim3(EDIM/128, 32, NEXP), blk, 0, stream>>>(
        h, fc1_t, h1, rowmap, counts, offs, EDIM, 1024);
    gemm_moe<3,0><<<dim3(DEMB/128, 32, NEXP), blk, 0, stream>>>(
        h1, fc2_t, oe, rowmap, counts, offs, DEMB, EDIM);
    combine_k<<<NTOK, blk, 0, stream>>>(oe, rowpos, wts, out);
}

// Round 8
// 537.976 us; speedup vs baseline: 1.0257x; 1.0257x over previous
//
#include <hip/hip_runtime.h>
#include <math.h>

#define NTOK 4096
#define DEMB 1024
#define TSEQ 2048
#define QKVS 3072
#define QKN  2048
#define EDIM 2048
#define NEXP 8

typedef unsigned short u16;
typedef unsigned int u32;
typedef __bf16 bf16_t;
typedef __bf16 bf16x8 __attribute__((ext_vector_type(8)));
typedef __bf16 bf16x4 __attribute__((ext_vector_type(4)));
typedef float f32x4 __attribute__((ext_vector_type(4)));

__device__ __forceinline__ f32x4 mfma16(bf16x8 a, bf16x8 b, f32x4 c) {
    return __builtin_amdgcn_mfma_f32_16x16x32_bf16(a, b, c, 0, 0, 0);
}
__device__ __forceinline__ void gll16(const void* g, void* l) {
    __builtin_amdgcn_global_load_lds((const __attribute__((address_space(1))) u32*)g,
                                     (__attribute__((address_space(3))) u32*)l, 16, 0, 0);
}
__device__ __forceinline__ u16 f2bf(float x) {
    union { __bf16 h; u16 u; } c; c.h = (__bf16)x; return c.u;
}

// ---------------- rmsnorm fp32 -> split bf16 (hi, lo) ----------------
__global__ __launch_bounds__(256) void rmsnorm_split_k(const float* __restrict__ x,
                                                       bf16_t* __restrict__ hi,
                                                       bf16_t* __restrict__ lo) {
    const int row = blockIdx.x;
    const float4 v = ((const float4*)(x + (size_t)row * DEMB))[threadIdx.x];
    float ss = v.x*v.x + v.y*v.y + v.z*v.z + v.w*v.w;
    #pragma unroll
    for (int off = 32; off; off >>= 1) ss += __shfl_xor(ss, off);
    __shared__ float wsum[4];
    if ((threadIdx.x & 63) == 0) wsum[threadIdx.x >> 6] = ss;
    __syncthreads();
    const float r = rsqrtf((wsum[0]+wsum[1]+wsum[2]+wsum[3]) * (1.0f/DEMB) + 1e-5f);
    const float f[4] = {v.x*r, v.y*r, v.z*r, v.w*r};
    bf16x4 hv, lv;
    #pragma unroll
    for (int j = 0; j < 4; j++) {
        const __bf16 hb = (__bf16)f[j];
        hv[j] = hb;
        lv[j] = (__bf16)(f[j] - (float)hb);
    }
    ((bf16x4*)(hi + (size_t)row*DEMB))[threadIdx.x] = hv;
    ((bf16x4*)(lo + (size_t)row*DEMB))[threadIdx.x] = lv;
}

// ---------------- rmsnorm fp32 -> plain bf16 ----------------
__global__ __launch_bounds__(256) void rmsnorm_bf_k(const float* __restrict__ x,
                                                    bf16_t* __restrict__ y) {
    const int row = blockIdx.x;
    const float4 v = ((const float4*)(x + (size_t)row * DEMB))[threadIdx.x];
    float ss = v.x*v.x + v.y*v.y + v.z*v.z + v.w*v.w;
    #pragma unroll
    for (int off = 32; off; off >>= 1) ss += __shfl_xor(ss, off);
    __shared__ float wsum[4];
    if ((threadIdx.x & 63) == 0) wsum[threadIdx.x >> 6] = ss;
    __syncthreads();
    const float r = rsqrtf((wsum[0]+wsum[1]+wsum[2]+wsum[3]) * (1.0f/DEMB) + 1e-5f);
    bf16x4 o;
    o[0] = (__bf16)(v.x*r); o[1] = (__bf16)(v.y*r);
    o[2] = (__bf16)(v.z*r); o[3] = (__bf16)(v.w*r);
    ((bf16x4*)(y + (size_t)row*DEMB))[threadIdx.x] = o;
}

// ---------------- weight transpose fp32 [K][M] -> split bf16 [M][K] ----------------
__global__ __launch_bounds__(256) void transp_split_k(const float* __restrict__ w,
                                                      bf16_t* __restrict__ wth,
                                                      bf16_t* __restrict__ wtl,
                                                      int K, int M) {
    __shared__ float t[32][33];
    const int m0 = blockIdx.x*32, k0 = blockIdx.y*32;
    const int tx = threadIdx.x & 31, ty = threadIdx.x >> 5;
    #pragma unroll
    for (int i = 0; i < 32; i += 8) t[ty+i][tx] = w[(size_t)(k0+ty+i)*M + m0+tx];
    __syncthreads();
    #pragma unroll
    for (int i = 0; i < 32; i += 8) {
        const float f = t[tx][ty+i];
        const __bf16 hb = (__bf16)f;
        wth[(size_t)(m0+ty+i)*K + k0+tx] = hb;
        wtl[(size_t)(m0+ty+i)*K + k0+tx] = (__bf16)(f - (float)hb);
    }
}

// ---------------- weight transpose fp32 [K][M] -> plain bf16 [M][K] (per expert) ------
__global__ __launch_bounds__(256) void transp_k(const float* __restrict__ w,
                                                bf16_t* __restrict__ wt,
                                                int K, int M) {
    __shared__ float t[32][33];
    const size_t eo = (size_t)blockIdx.z * K * M;
    w += eo; wt += eo;
    const int m0 = blockIdx.x*32, k0 = blockIdx.y*32;
    const int tx = threadIdx.x & 31, ty = threadIdx.x >> 5;
    #pragma unroll
    for (int i = 0; i < 32; i += 8) t[ty+i][tx] = w[(size_t)(k0+ty+i)*M + m0+tx];
    __syncthreads();
    #pragma unroll
    for (int i = 0; i < 32; i += 8) wt[(size_t)(m0+ty+i)*K + k0+tx] = (__bf16)t[tx][ty+i];
}

// ---------------- split-bf16 GEMM: C = (Ah+Al)(Bh+Bl)^T, 3 MFMA products ----
// LDS: packed HI|LO rows [128][8 chunks x 16B]; slot(row,c) holds data chunk d=c^(row&7)
// (d<4 -> HI k-chunk d, d>=4 -> LO k-chunk d-4). 128B row stride + XOR => 2-way banks (free).
// Staging pre-swizzles the GLOBAL source (linear LDS dest, rule #21).
// EPI 1: fp32 store = res + acc
// EPI 3: QKV epilogue -> Q (x0.125) and K split into qk [tok][2048]; V split into V^T
template<int EPI>
__global__ __launch_bounds__(256) void gemm_split(const bf16_t* __restrict__ Ah,
                                                  const bf16_t* __restrict__ Al,
                                                  const bf16_t* __restrict__ Bh,
                                                  const bf16_t* __restrict__ Bl,
                                                  const float* __restrict__ res,
                                                  float* __restrict__ C,
                                                  bf16_t* __restrict__ qkh,
                                                  bf16_t* __restrict__ qkl,
                                                  bf16_t* __restrict__ vth,
                                                  bf16_t* __restrict__ vtl,
                                                  int N, int K) {
    __shared__ u16 As[128*64];
    __shared__ u16 Bs[128*64];
    const int tid = threadIdx.x;
    const int lane = tid & 63, w = tid >> 6;
    const int lr = lane & 15, lg = lane >> 4;
    const int wm = w >> 1, wn = w & 1;
    // XCD-aware bijective block swizzle (all grids here have nwg % 8 == 0)
    const int nbx = gridDim.x;
    const int nwg = gridDim.x * gridDim.y;
    int flat = blockIdx.y * nbx + blockIdx.x;
    flat = (flat & 7) * (nwg >> 3) + (flat >> 3);
    const int m0 = (flat / nbx) * 128, n0 = (flat % nbx) * 128;

    const int srow = tid >> 3;                 // 0..31
    const int sd   = (tid & 7) ^ (srow & 7);   // data chunk this thread fetches
    const int kofs = (sd & 3) * 8;
    const bf16_t* Asrc = (sd < 4) ? Ah : Al;
    const bf16_t* Bsrc = (sd < 4) ? Bh : Bl;
    const bf16_t* pa0 = Asrc + (size_t)(m0 + srow     ) * K + kofs;
    const bf16_t* pa1 = Asrc + (size_t)(m0 + srow + 32) * K + kofs;
    const bf16_t* pa2 = Asrc + (size_t)(m0 + srow + 64) * K + kofs;
    const bf16_t* pa3 = Asrc + (size_t)(m0 + srow + 96) * K + kofs;
    const bf16_t* pb0 = Bsrc + (size_t)(n0 + srow     ) * K + kofs;
    const bf16_t* pb1 = Bsrc + (size_t)(n0 + srow + 32) * K + kofs;
    const bf16_t* pb2 = Bsrc + (size_t)(n0 + srow + 64) * K + kofs;
    const bf16_t* pb3 = Bsrc + (size_t)(n0 + srow + 96) * K + kofs;
    char* dA = (char*)As + tid*16;
    char* dB = (char*)Bs + tid*16;
    const int ca = (lg ^ (lr & 7)) * 8;        // HI chunk slot (u16 offset in row)
    f32x4 acc[4][4] = {};
    for (int k0 = 0; k0 < K; k0 += 32) {
        __syncthreads();
        gll16(pa0 + k0, dA);          gll16(pa1 + k0, dA + 4096);
        gll16(pa2 + k0, dA + 8192);   gll16(pa3 + k0, dA + 12288);
        gll16(pb0 + k0, dB);          gll16(pb1 + k0, dB + 4096);
        gll16(pb2 + k0, dB + 8192);   gll16(pb3 + k0, dB + 12288);
        __syncthreads();
        bf16x8 ah[4], al[4], bh[4], bl[4];
        #pragma unroll
        for (int i = 0; i < 4; i++) {
            const int ao = (wm*64 + i*16 + lr)*64 + ca;
            const int bo = (wn*64 + i*16 + lr)*64 + ca;
            ah[i] = *(const bf16x8*)&As[ao];
            al[i] = *(const bf16x8*)&As[ao ^ 32];   // chunk c^4 = LO slot
            bh[i] = *(const bf16x8*)&Bs[bo];
            bl[i] = *(const bf16x8*)&Bs[bo ^ 32];
        }
        #pragma unroll
        for (int i = 0; i < 4; i++)
            #pragma unroll
            for (int j = 0; j < 4; j++) {
                acc[i][j] = mfma16(ah[i], bh[j], acc[i][j]);
                acc[i][j] = mfma16(ah[i], bl[j], acc[i][j]);
                acc[i][j] = mfma16(al[i], bh[j], acc[i][j]);
            }
    }
    #pragma unroll
    for (int i = 0; i < 4; i++) {
        #pragma unroll
        for (int j = 0; j < 4; j++) {
            const int row = m0 + wm*64 + i*16 + lg*4;
            const int col = n0 + wn*64 + j*16 + lr;
            const f32x4 v = acc[i][j];
            if (EPI == 1) {
                #pragma unroll
                for (int r = 0; r < 4; r++) {
                    const size_t o = (size_t)(row + r) * N + col;
                    C[o] = res[o] + v[r];
                }
            } else {
                if (col < QKN) {   // Q (scaled) or K
                    const float sc = (col < DEMB) ? 0.125f : 1.0f;
                    #pragma unroll
                    for (int r = 0; r < 4; r++) {
                        const size_t o = (size_t)(row + r) * QKN + col;
                        const float f = v[r] * sc;
                        const __bf16 hb = (__bf16)f;
                        qkh[o] = hb;
                        qkl[o] = (__bf16)(f - (float)hb);
                    }
                } else {           // V -> V^T [ (b*16+h)*64 + d ][ t ]
                    const int d = col - QKN;
                    const int hh = d >> 6, dd = d & 63;
                    const int bb = row >> 11, t = row & 2047;
                    const size_t base = ((size_t)(bb*16 + hh)*64 + dd) * TSEQ + t;
                    #pragma unroll
                    for (int r = 0; r < 4; r++) {
                        const float f = v[r];
                        const __bf16 hb = (__bf16)f;
                        vth[base + r] = hb;
                        vtl[base + r] = (__bf16)(f - (float)hb);
                    }
                }
            }
        }
    }
}

// ---------------- grouped per-expert bf16 GEMM (EPI 2: relu^2; EPI 3: plain) ----------
// LDS: packed row-pairs [64 rp][8 chunks x 16B]; slot(rp,c) holds d=c^(rp&7):
// matrix row = 2rp+(d>>2), k-chunk = d&3. Pre-swizzled global source, linear dest.
template<int EPI, int GATHER>
__global__ __launch_bounds__(256) void gemm_moe(const bf16_t* __restrict__ A,
                                                const bf16_t* __restrict__ Ball,
                                                bf16_t* __restrict__ C,
                                                const int* __restrict__ rowmap,
                                                const int* __restrict__ counts,
                                                const int* __restrict__ offs,
                                                int N, int K) {
    const int e = blockIdx.z;
    const int cnt = counts[e];
    if ((int)blockIdx.y * 128 >= cnt) return;
    const int base = offs[e];
    const bf16_t* Bt = Ball + (size_t)e * N * K;
    __shared__ u16 As[64*64];
    __shared__ u16 Bs[64*64];
    const int tid = threadIdx.x;
    const int lane = tid & 63, w = tid >> 6;
    const int lr = lane & 15, lg = lane >> 4;
    const int wm = w >> 1, wn = w & 1;
    const int m0 = blockIdx.y * 128, n0 = blockIdx.x * 128;

    const int srp = tid >> 3;                  // 0..31 (rowpair)
    const int sd  = (tid & 7) ^ (srp & 7);
    const int smrow = 2*srp + (sd >> 2);       // 0..63
    const int kofs  = (sd & 3) * 8;
    const int l0 = min(m0 + smrow, cnt - 1), l1 = min(m0 + 64 + smrow, cnt - 1);
    const size_t r0 = GATHER ? (size_t)rowmap[base + l0] : (size_t)(base + l0);
    const size_t r1 = GATHER ? (size_t)rowmap[base + l1] : (size_t)(base + l1);
    const bf16_t* pa0 = A + r0 * K + kofs;
    const bf16_t* pa1 = A + r1 * K + kofs;
    const bf16_t* pb0 = Bt + (size_t)(n0 + smrow)      * K + kofs;
    const bf16_t* pb1 = Bt + (size_t)(n0 + 64 + smrow) * K + kofs;
    char* dA = (char*)As + tid*16;
    char* dB = (char*)Bs + tid*16;
    const int cs = (((lr & 1) << 2) + lg) ^ ((lr >> 1) & 7);   // read chunk slot
    f32x4 acc[4][4] = {};
    for (int k0 = 0; k0 < K; k0 += 32) {
        __syncthreads();
        gll16(pa0 + k0, dA); gll16(pa1 + k0, dA + 4096);
        gll16(pb0 + k0, dB); gll16(pb1 + k0, dB + 4096);
        __syncthreads();
        bf16x8 af[4], bfr[4];
        #pragma unroll
        for (int i = 0; i < 4; i++) {
            af[i]  = *(const bf16x8*)&As[(wm*32 + i*8 + (lr>>1))*64 + cs*8];
            bfr[i] = *(const bf16x8*)&Bs[(wn*32 + i*8 + (lr>>1))*64 + cs*8];
        }
        #pragma unroll
        for (int i = 0; i < 4; i++)
            #pragma unroll
            for (int j = 0; j < 4; j++)
                acc[i][j] = mfma16(af[i], bfr[j], acc[i][j]);
    }
    #pragma unroll
    for (int i = 0; i < 4; i++) {
        #pragma unroll
        for (int j = 0; j < 4; j++) {
            const int rowl = m0 + wm*64 + i*16 + lg*4;
            const int col  = n0 + wn*64 + j*16 + lr;
            const f32x4 v = acc[i][j];
            #pragma unroll
            for (int r = 0; r < 4; r++) {
                if (rowl + r < cnt) {
                    float xv = v[r];
                    if (EPI == 2) { xv = fmaxf(xv, 0.f); xv = xv * xv; }
                    C[(size_t)(base + rowl + r) * N + col] = (__bf16)xv;
                }
            }
        }
    }
}

// ---------------- split-bf16 MFMA flash attention, causal, balanced pairs ----------------
// grid (16,16,2): block handles q-tiles qa=bx and qb=31-bx (64 rows each) in ONE kv sweep.
// 4 waves x 16 q-rows per tile. K from qk buffer; V^T pre-transposed in global.
__global__ __launch_bounds__(256) void attn_mfma(const bf16_t* __restrict__ qkh,
                                                 const bf16_t* __restrict__ qkl,
                                                 const bf16_t* __restrict__ vth,
                                                 const bf16_t* __restrict__ vtl,
                                                 bf16_t* __restrict__ aoh,
                                                 bf16_t* __restrict__ aol) {
    __shared__ u16 KsH[64*64];   // [kv][d], chunk-swizzled c^=kv&7
    __shared__ u16 KsL[64*64];
    __shared__ u16 VtH[64*64];   // [d][kv], chunk-swizzled c^=d&7 (src pre-swizzled)
    __shared__ u16 VtL[64*64];
    __shared__ u16 P_H[4*16*72]; // per-wave P / output bounce
    __shared__ u16 P_L[4*16*72];
    const int tid = threadIdx.x, lane = tid & 63, wv = tid >> 6;
    const int lr = lane & 15, lg = lane >> 4;
    const int h = blockIdx.y, b = blockIdx.z;
    const int qa = blockIdx.x, qb = 31 - qa;
    u16* plwH = P_H + wv * 16 * 72;
    u16* plwL = P_L + wv * 16 * 72;
    const int wq0A = qa*64 + wv*16;
    const int wq0B = qb*64 + wv*16;

    bf16x8 qAh[2], qAl[2], qBh[2], qBl[2];
    #pragma unroll
    for (int kf = 0; kf < 2; kf++) {
        const size_t qoA = (size_t)(b*TSEQ + wq0A + lr)*QKN + h*64 + kf*32 + lg*8;
        const size_t qoB = (size_t)(b*TSEQ + wq0B + lr)*QKN + h*64 + kf*32 + lg*8;
        qAh[kf] = *(const bf16x8*)(qkh + qoA);
        qAl[kf] = *(const bf16x8*)(qkl + qoA);
        qBh[kf] = *(const bf16x8*)(qkh + qoB);
        qBl[kf] = *(const bf16x8*)(qkl + qoB);
    }

    f32x4 ofA[4] = {}, ofB[4] = {};
    float mA = -1e30f, lA = 0.f, mB = -1e30f, lB = 0.f;

    const int skv = tid >> 3;                 // 0..31
    const int pst = tid & 7;
    const int chs = pst ^ (skv & 7);          // swizzled source chunk (K and V^T alike)
    const int bh = b*16 + h;
    const bf16_t* kh = qkh + 1024;
    const bf16_t* kl = qkl + 1024;
    const size_t vrow0 = (size_t)(bh*64 + skv)      * TSEQ;
    const size_t vrow1 = (size_t)(bh*64 + skv + 32) * TSEQ;

    auto step = [&](f32x4 (&of)[4], float& mrun, float& lrun,
                    const bf16x8 (&qfh)[2], const bf16x8 (&qfl)[2],
                    const int wq0, const bool diag, const int kvb) {
        f32x4 sf[4] = {};
        #pragma unroll
        for (int kf = 0; kf < 2; kf++)
            #pragma unroll
            for (int f = 0; f < 4; f++) {
                const int idx = (f*16 + lr)*64 + ((kf*32 + lg*8) ^ ((lr & 7) << 3));
                const bf16x8 ah = *(const bf16x8*)&KsH[idx];
                const bf16x8 al = *(const bf16x8*)&KsL[idx];
                sf[f] = mfma16(ah, qfh[kf], sf[f]);
                sf[f] = mfma16(ah, qfl[kf], sf[f]);
                sf[f] = mfma16(al, qfh[kf], sf[f]);
            }
        if (diag) {
            #pragma unroll
            for (int f = 0; f < 4; f++)
                #pragma unroll
                for (int r = 0; r < 4; r++)
                    if (kvb + f*16 + lg*4 + r > wq0 + lr) sf[f][r] = -1e30f;
        }
        float tm = -1e30f;
        #pragma unroll
        for (int f = 0; f < 4; f++)
            tm = fmaxf(tm, fmaxf(fmaxf(sf[f][0], sf[f][1]), fmaxf(sf[f][2], sf[f][3])));
        tm = fmaxf(tm, __shfl_xor(tm, 16));
        tm = fmaxf(tm, __shfl_xor(tm, 32));
        const float mnew = fmaxf(mrun, tm);
        const float fac = __expf(mrun - mnew);
        mrun = mnew;
        float ps = 0.f;
        #pragma unroll
        for (int f = 0; f < 4; f++) {
            float p[4];
            #pragma unroll
            for (int r = 0; r < 4; r++) { p[r] = __expf(sf[f][r] - mnew); ps += p[r]; }
            u16 hb4[4], lb4[4];
            #pragma unroll
            for (int r = 0; r < 4; r++) {
                const __bf16 hb = (__bf16)p[r];
                hb4[r] = f2bf(p[r]);
                lb4[r] = f2bf(p[r] - (float)hb);
            }
            u32* pwh = (u32*)&plwH[lr*72 + f*16 + lg*4];
            u32* pwl = (u32*)&plwL[lr*72 + f*16 + lg*4];
            pwh[0] = (u32)hb4[0] | ((u32)hb4[1] << 16);
            pwh[1] = (u32)hb4[2] | ((u32)hb4[3] << 16);
            pwl[0] = (u32)lb4[0] | ((u32)lb4[1] << 16);
            pwl[1] = (u32)lb4[2] | ((u32)lb4[3] << 16);
        }
        ps += __shfl_xor(ps, 16);
        ps += __shfl_xor(ps, 32);
        lrun = lrun*fac + ps;
        #pragma unroll
        for (int f2 = 0; f2 < 4; f2++)
            #pragma unroll
            for (int r = 0; r < 4; r++) of[f2][r] *= fac;
        #pragma unroll
        for (int hf = 0; hf < 2; hf++) {
            const bf16x8 pbh = *(const bf16x8*)&plwH[lr*72 + hf*32 + lg*8];
            const bf16x8 pbl = *(const bf16x8*)&plwL[lr*72 + hf*32 + lg*8];
            #pragma unroll
            for (int f2 = 0; f2 < 4; f2++) {
                const int vidx = (f2*16 + lr)*64 + (((hf*4 + lg) ^ (lr & 7)) << 3);
                const bf16x8 vah = *(const bf16x8*)&VtH[vidx];
                const bf16x8 val = *(const bf16x8*)&VtL[vidx];
                of[f2] = mfma16(vah, pbh, of[f2]);
                of[f2] = mfma16(vah, pbl, of[f2]);
                of[f2] = mfma16(val, pbh, of[f2]);
            }
        }
    };

    for (int kt = 0; kt <= qb; kt++) {
        __syncthreads();
        const size_t krow = (size_t)(b*TSEQ + kt*64 + skv)*QKN + h*64;
        gll16(kh + krow + chs*8,                     (char*)KsH + tid*16);
        gll16(kh + krow + (size_t)32*QKN + chs*8,    (char*)KsH + 4096 + tid*16);
        gll16(kl + krow + chs*8,                     (char*)KsL + tid*16);
        gll16(kl + krow + (size_t)32*QKN + chs*8,    (char*)KsL + 4096 + tid*16);
        gll16(vth + vrow0 + kt*64 + chs*8,           (char*)VtH + tid*16);
        gll16(vth + vrow1 + kt*64 + chs*8,           (char*)VtH + 4096 + tid*16);
        gll16(vtl + vrow0 + kt*64 + chs*8,           (char*)VtL + tid*16);
        gll16(vtl + vrow1 + kt*64 + chs*8,           (char*)VtL + 4096 + tid*16);
        __syncthreads();
        if (kt <= qa) step(ofA, mA, lA, qAh, qAl, wq0A, kt == qa, kt*64);
        step(ofB, mB, lB, qBh, qBl, wq0B, kt == qb, kt*64);
    }

    // epilogue per tile: normalize, split, bounce through per-wave LDS, coalesced store
    const float invA = 1.f / lA, invB = 1.f / lB;
    #pragma unroll
    for (int f2 = 0; f2 < 4; f2++) {
        u16 hb4[4], lb4[4];
        #pragma unroll
        for (int r = 0; r < 4; r++) {
            const float f = ofA[f2][r] * invA;
            const __bf16 hb = (__bf16)f;
            hb4[r] = f2bf(f);
            lb4[r] = f2bf(f - (float)hb);
        }
        u32* pwh = (u32*)&plwH[lr*72 + f2*16 + lg*4];
        u32* pwl = (u32*)&plwL[lr*72 + f2*16 + lg*4];
        pwh[0] = (u32)hb4[0] | ((u32)hb4[1] << 16);
        pwh[1] = (u32)hb4[2] | ((u32)hb4[3] << 16);
        pwl[0] = (u32)lb4[0] | ((u32)lb4[1] << 16);
        pwl[1] = (u32)lb4[2] | ((u32)lb4[3] << 16);
    }
    asm volatile("s_waitcnt lgkmcnt(0)" ::: "memory");
    __builtin_amdgcn_sched_barrier(0);
    #pragma unroll
    for (int pass = 0; pass < 2; pass++) {
        const int qlr = pass*8 + (lane >> 3);
        const int ch = (lane & 7) * 8;
        const bf16x8 oh = *(const bf16x8*)&plwH[qlr*72 + ch];
        const bf16x8 ol = *(const bf16x8*)&plwL[qlr*72 + ch];
        const size_t go = (size_t)(b*TSEQ + wq0A + qlr) * DEMB + h*64 + ch;
        *(bf16x8*)(aoh + go) = oh;
        *(bf16x8*)(aol + go) = ol;
    }
    asm volatile("s_waitcnt lgkmcnt(0)" ::: "memory");
    __builtin_amdgcn_sched_barrier(0);
    #pragma unroll
    for (int f2 = 0; f2 < 4; f2++) {
        u16 hb4[4], lb4[4];
        #pragma unroll
        for (int r = 0; r < 4; r++) {
            const float f = ofB[f2][r] * invB;
            const __bf16 hb = (__bf16)f;
            hb4[r] = f2bf(f);
            lb4[r] = f2bf(f - (float)hb);
        }
        u32* pwh = (u32*)&plwH[lr*72 + f2*16 + lg*4];
        u32* pwl = (u32*)&plwL[lr*72 + f2*16 + lg*4];
        pwh[0] = (u32)hb4[0] | ((u32)hb4[1] << 16);
        pwh[1] = (u32)hb4[2] | ((u32)hb4[3] << 16);
        pwl[0] = (u32)lb4[0] | ((u32)lb4[1] << 16);
        pwl[1] = (u32)lb4[2] | ((u32)lb4[3] << 16);
    }
    asm volatile("s_waitcnt lgkmcnt(0)" ::: "memory");
    __builtin_amdgcn_sched_barrier(0);
    #pragma unroll
    for (int pass = 0; pass < 2; pass++) {
        const int qlr = pass*8 + (lane >> 3);
        const int ch = (lane & 7) * 8;
        const bf16x8 oh = *(const bf16x8*)&plwH[qlr*72 + ch];
        const bf16x8 ol = *(const bf16x8*)&plwL[qlr*72 + ch];
        const size_t go = (size_t)(b*TSEQ + wq0B + qlr) * DEMB + h*64 + ch;
        *(bf16x8*)(aoh + go) = oh;
        *(bf16x8*)(aol + go) = ol;
    }
}

// ---------------- MoE routing (fp32, rmsnorm folded in) ----------------
__global__ void zero8(int* c) { if (threadIdx.x < NEXP) c[threadIdx.x] = 0; }

__global__ __launch_bounds__(256) void router_k(const float* __restrict__ xout,
                                                const float* __restrict__ rw,
                                                int* __restrict__ idx,
                                                float* __restrict__ wts,
                                                int* __restrict__ pos,
                                                int* __restrict__ counts) {
    const int tok = blockIdx.x * 4 + (threadIdx.x >> 6);
    const int lane = threadIdx.x & 63;
    const float* xr = xout + (size_t)tok * DEMB;
    float ss = 0.f;
    float acc[NEXP];
    #pragma unroll
    for (int e = 0; e < NEXP; e++) acc[e] = 0.f;
    for (int kk = lane; kk < DEMB; kk += 64) {
        const float xv = xr[kk];
        ss += xv * xv;
        #pragma unroll
        for (int e = 0; e < NEXP; e++) acc[e] += xv * rw[kk*NEXP + e];
    }
    #pragma unroll
    for (int off = 32; off; off >>= 1) ss += __shfl_xor(ss, off);
    #pragma unroll
    for (int e = 0; e < NEXP; e++) {
        #pragma unroll
        for (int off = 32; off; off >>= 1) acc[e] += __shfl_xor(acc[e], off);
    }
    if (lane == 0) {
        const float r = rsqrtf(ss * (1.0f/DEMB) + 1e-5f);
        float v[NEXP];
        #pragma unroll
        for (int e = 0; e < NEXP; e++) v[e] = acc[e] * r;
        int b0 = 0; float v0 = v[0];
        #pragma unroll
        for (int e = 1; e < NEXP; e++) if (v[e] > v0) { v0 = v[e]; b0 = e; }
        int b1 = -1; float v1 = -1e30f;
        #pragma unroll
        for (int e = 0; e < NEXP; e++) if (e != b0 && v[e] > v1) { v1 = v[e]; b1 = e; }
        const float w0 = 1.f / (1.f + __expf(v1 - v0));
        idx[tok*2+0] = b0; idx[tok*2+1] = b1;
        wts[tok*2+0] = w0; wts[tok*2+1] = 1.f - w0;
        pos[tok*2+0] = atomicAdd(&counts[b0], 1);
        pos[tok*2+1] = atomicAdd(&counts[b1], 1);
    }
}

__global__ void offsets_k(const int* __restrict__ counts, int* __restrict__ offs) {
    if (threadIdx.x == 0) {
        int s = 0;
        for (int e = 0; e < NEXP; e++) { offs[e] = s; s += counts[e]; }
    }
}

__global__ __launch_bounds__(256) void buildmap_k(const int* __restrict__ idx,
                                                  const int* __restrict__ pos,
                                                  const int* __restrict__ offs,
                                                  int* __restrict__ rowmap,
                                                  int* __restrict__ rowpos) {
    const int n = blockIdx.x * 256 + threadIdx.x;
    #pragma unroll
    for (int s = 0; s < 2; s++) {
        const int e = idx[n*2+s];
        const int r = offs[e] + pos[n*2+s];
        rowmap[r] = n;
        rowpos[n*2+s] = r;
    }
}

__global__ __launch_bounds__(256) void combine_k(const bf16_t* __restrict__ oe,
                                                 const int* __restrict__ rowpos,
                                                 const float* __restrict__ wts,
                                                 float* __restrict__ out) {
    const int n = blockIdx.x;
    const int r0 = rowpos[n*2+0], r1 = rowpos[n*2+1];
    const float w0 = wts[n*2+0], w1 = wts[n*2+1];
    const int c = threadIdx.x * 4;
    const bf16x4 a  = *(const bf16x4*)(oe + (size_t)r0*DEMB + c);
    const bf16x4 b4 = *(const bf16x4*)(oe + (size_t)r1*DEMB + c);
    float4* op = (float4*)(out + (size_t)n*DEMB + c);
    float4 o = *op;
    o.x += w0*(float)a[0] + w1*(float)b4[0];
    o.y += w0*(float)a[1] + w1*(float)b4[1];
    o.z += w0*(float)a[2] + w1*(float)b4[2];
    o.w += w0*(float)a[3] + w1*(float)b4[3];
    *op = o;
}

extern "C" void kernel_launch(void* const* d_in, const int* in_sizes, int n_in,
                              void* d_out, int out_size, void* d_ws, size_t ws_size,
                              hipStream_t stream) {
    (void)in_sizes; (void)n_in; (void)out_size; (void)ws_size;
    const float* x   = (const float*)d_in[0];
    const float* wq  = (const float*)d_in[1];
    const float* wk  = (const float*)d_in[2];
    const float* wv  = (const float*)d_in[3];
    const float* wo  = (const float*)d_in[4];
    const float* rw  = (const float*)d_in[5];
    const float* fc1 = (const float*)d_in[6];
    const float* fc2 = (const float*)d_in[7];
    float* out = (float*)d_out;
    char* ws = (char*)d_ws;
    const size_t MB = 1024*1024;

    bf16_t* wqkv_h = (bf16_t*)(ws);
    bf16_t* wqkv_l = (bf16_t*)(ws + 6*MB);
    bf16_t* wo_h   = (bf16_t*)(ws + 12*MB);
    bf16_t* wo_l   = (bf16_t*)(ws + 14*MB);
    bf16_t* qk_h   = (bf16_t*)(ws + 16*MB);
    bf16_t* qk_l   = (bf16_t*)(ws + 32*MB);
    bf16_t* vt_h   = (bf16_t*)(ws + 48*MB);
    bf16_t* vt_l   = (bf16_t*)(ws + 56*MB);
    bf16_t* fc1_t  = (bf16_t*)(ws + 16*MB);
    bf16_t* fc2_t  = (bf16_t*)(ws + 48*MB);
    bf16_t* h_hi   = (bf16_t*)(ws + 64*MB);
    bf16_t* h_lo   = (bf16_t*)(ws + 72*MB);
    bf16_t* ao_h   = (bf16_t*)(ws + 64*MB);
    bf16_t* ao_l   = (bf16_t*)(ws + 72*MB);
    bf16_t* h      = (bf16_t*)(ws + 80*MB);
    bf16_t* h1     = (bf16_t*)(ws + 88*MB);
    bf16_t* oe     = (bf16_t*)(ws);
    char* meta = ws + 120*MB;
    int*   idx    = (int*)(meta);
    int*   pos    = (int*)(meta + 64*1024);
    int*   rowmap = (int*)(meta + 128*1024);
    int*   rowpos = (int*)(meta + 192*1024);
    float* wts    = (float*)(meta + 256*1024);
    int*   counts = (int*)(meta + 320*1024);
    int*   offs   = (int*)(meta + 320*1024 + 256);

    const dim3 blk(256);

    // ---- attention path ----
    transp_split_k<<<dim3(32,32), blk, 0, stream>>>(wq, wqkv_h,               wqkv_l,               1024, 1024);
    transp_split_k<<<dim3(32,32), blk, 0, stream>>>(wk, wqkv_h + 1024*1024,   wqkv_l + 1024*1024,   1024, 1024);
    transp_split_k<<<dim3(32,32), blk, 0, stream>>>(wv, wqkv_h + 2*1024*1024, wqkv_l + 2*1024*1024, 1024, 1024);
    transp_split_k<<<dim3(32,32), blk, 0, stream>>>(wo, wo_h,                 wo_l,                 1024, 1024);
    rmsnorm_split_k<<<NTOK, blk, 0, stream>>>(x, h_hi, h_lo);
    gemm_split<3><<<dim3(QKVS/128, NTOK/128), blk, 0, stream>>>(
        h_hi, h_lo, wqkv_h, wqkv_l, nullptr, nullptr, qk_h, qk_l, vt_h, vt_l, QKVS, 1024);
    attn_mfma<<<dim3(16, 16, 2), blk, 0, stream>>>(qk_h, qk_l, vt_h, vt_l, ao_h, ao_l);
    gemm_split<1><<<dim3(DEMB/128, NTOK/128), blk, 0, stream>>>(
        ao_h, ao_l, wo_h, wo_l, x, out, nullptr, nullptr, nullptr, nullptr, DEMB, 1024);

    // ---- MoE path (fp32 router, bf16 experts) ----
    transp_k<<<dim3(64,32,8), blk, 0, stream>>>(fc1, fc1_t, 1024, 2048);
    transp_k<<<dim3(32,64,8), blk, 0, stream>>>(fc2, fc2_t, 2048, 1024);
    rmsnorm_bf_k<<<NTOK, blk, 0, stream>>>(out, h);
    zero8<<<1, 64, 0, stream>>>(counts);
    router_k<<<NTOK/4, blk, 0, stream>>>(out, rw, idx, wts, pos, counts);
    offsets_k<<<1, 64, 0, stream>>>(counts, offs);
    buildmap_k<<<NTOK/256, blk, 0, stream>>>(idx, pos, offs, rowmap, rowpos);
    gemm_moe<2,1><<<dim3(EDIM/128, 32, NEXP), blk, 0, stream>>>(
        h, fc1_t, h1, rowmap, counts, offs, EDIM, 1024);
    gemm_moe<3,0><<<dim3(DEMB/128, 32, NEXP), blk, 0, stream>>>(
        h1, fc2_t, oe, rowmap, counts, offs, DEMB, EDIM);
    combine_k<<<NTOK, blk, 0, stream>>>(oe, rowpos, wts, out);
}

// Round 9
// 526.012 us; speedup vs baseline: 1.0491x; 1.0227x over previous
//
#include <hip/hip_runtime.h>
#include <math.h>

#define NTOK 4096
#define DEMB 1024
#define TSEQ 2048
#define QKVS 3072
#define QKN  2048
#define EDIM 2048
#define NEXP 8

typedef unsigned short u16;
typedef unsigned int u32;
typedef __bf16 bf16_t;
typedef __bf16 bf16x8 __attribute__((ext_vector_type(8)));
typedef __bf16 bf16x4 __attribute__((ext_vector_type(4)));
typedef float f32x4 __attribute__((ext_vector_type(4)));

__device__ __forceinline__ f32x4 mfma16(bf16x8 a, bf16x8 b, f32x4 c) {
    return __builtin_amdgcn_mfma_f32_16x16x32_bf16(a, b, c, 0, 0, 0);
}
__device__ __forceinline__ void gll16(const void* g, void* l) {
    __builtin_amdgcn_global_load_lds((const __attribute__((address_space(1))) u32*)g,
                                     (__attribute__((address_space(3))) u32*)l, 16, 0, 0);
}
__device__ __forceinline__ u16 f2bf(float x) {
    union { __bf16 h; u16 u; } c; c.h = (__bf16)x; return c.u;
}

// ---------------- rmsnorm fp32 -> split bf16 (hi, lo) ----------------
__global__ __launch_bounds__(256) void rmsnorm_split_k(const float* __restrict__ x,
                                                       bf16_t* __restrict__ hi,
                                                       bf16_t* __restrict__ lo) {
    const int row = blockIdx.x;
    const float4 v = ((const float4*)(x + (size_t)row * DEMB))[threadIdx.x];
    float ss = v.x*v.x + v.y*v.y + v.z*v.z + v.w*v.w;
    #pragma unroll
    for (int off = 32; off; off >>= 1) ss += __shfl_xor(ss, off);
    __shared__ float wsum[4];
    if ((threadIdx.x & 63) == 0) wsum[threadIdx.x >> 6] = ss;
    __syncthreads();
    const float r = rsqrtf((wsum[0]+wsum[1]+wsum[2]+wsum[3]) * (1.0f/DEMB) + 1e-5f);
    const float f[4] = {v.x*r, v.y*r, v.z*r, v.w*r};
    bf16x4 hv, lv;
    #pragma unroll
    for (int j = 0; j < 4; j++) {
        const __bf16 hb = (__bf16)f[j];
        hv[j] = hb;
        lv[j] = (__bf16)(f[j] - (float)hb);
    }
    ((bf16x4*)(hi + (size_t)row*DEMB))[threadIdx.x] = hv;
    ((bf16x4*)(lo + (size_t)row*DEMB))[threadIdx.x] = lv;
}

// ---------------- rmsnorm fp32 -> plain bf16 ----------------
__global__ __launch_bounds__(256) void rmsnorm_bf_k(const float* __restrict__ x,
                                                    bf16_t* __restrict__ y) {
    const int row = blockIdx.x;
    const float4 v = ((const float4*)(x + (size_t)row * DEMB))[threadIdx.x];
    float ss = v.x*v.x + v.y*v.y + v.z*v.z + v.w*v.w;
    #pragma unroll
    for (int off = 32; off; off >>= 1) ss += __shfl_xor(ss, off);
    __shared__ float wsum[4];
    if ((threadIdx.x & 63) == 0) wsum[threadIdx.x >> 6] = ss;
    __syncthreads();
    const float r = rsqrtf((wsum[0]+wsum[1]+wsum[2]+wsum[3]) * (1.0f/DEMB) + 1e-5f);
    bf16x4 o;
    o[0] = (__bf16)(v.x*r); o[1] = (__bf16)(v.y*r);
    o[2] = (__bf16)(v.z*r); o[3] = (__bf16)(v.w*r);
    ((bf16x4*)(y + (size_t)row*DEMB))[threadIdx.x] = o;
}

// ---------------- weight transpose fp32 [K][M] -> split bf16 [M][K] ----------------
__global__ __launch_bounds__(256) void transp_split_k(const float* __restrict__ w,
                                                      bf16_t* __restrict__ wth,
                                                      bf16_t* __restrict__ wtl,
                                                      int K, int M) {
    __shared__ float t[32][33];
    const int m0 = blockIdx.x*32, k0 = blockIdx.y*32;
    const int tx = threadIdx.x & 31, ty = threadIdx.x >> 5;
    #pragma unroll
    for (int i = 0; i < 32; i += 8) t[ty+i][tx] = w[(size_t)(k0+ty+i)*M + m0+tx];
    __syncthreads();
    #pragma unroll
    for (int i = 0; i < 32; i += 8) {
        const float f = t[tx][ty+i];
        const __bf16 hb = (__bf16)f;
        wth[(size_t)(m0+ty+i)*K + k0+tx] = hb;
        wtl[(size_t)(m0+ty+i)*K + k0+tx] = (__bf16)(f - (float)hb);
    }
}

// ---------------- weight transpose fp32 [K][M] -> plain bf16 [M][K] (per expert) ------
__global__ __launch_bounds__(256) void transp_k(const float* __restrict__ w,
                                                bf16_t* __restrict__ wt,
                                                int K, int M) {
    __shared__ float t[32][33];
    const size_t eo = (size_t)blockIdx.z * K * M;
    w += eo; wt += eo;
    const int m0 = blockIdx.x*32, k0 = blockIdx.y*32;
    const int tx = threadIdx.x & 31, ty = threadIdx.x >> 5;
    #pragma unroll
    for (int i = 0; i < 32; i += 8) t[ty+i][tx] = w[(size_t)(k0+ty+i)*M + m0+tx];
    __syncthreads();
    #pragma unroll
    for (int i = 0; i < 32; i += 8) wt[(size_t)(m0+ty+i)*K + k0+tx] = (__bf16)t[tx][ty+i];
}

// ---------------- split-bf16 GEMM: C = (Ah+Al)(Bh+Bl)^T, 3 MFMA products ----
// 2-phase pipeline: double-buffered LDS, STAGE(next) issued before compute(cur),
// single vmcnt(0)+barrier per K-step (T3 minimum recipe).
// LDS rows packed HI|LO [128][8 chunks x 16B], slot(row,c) = data chunk c^(row&7).
template<int EPI>
__global__ __launch_bounds__(256) void gemm_split(const bf16_t* __restrict__ Ah,
                                                  const bf16_t* __restrict__ Al,
                                                  const bf16_t* __restrict__ Bh,
                                                  const bf16_t* __restrict__ Bl,
                                                  const float* __restrict__ res,
                                                  float* __restrict__ C,
                                                  bf16_t* __restrict__ qkh,
                                                  bf16_t* __restrict__ qkl,
                                                  bf16_t* __restrict__ vth,
                                                  bf16_t* __restrict__ vtl,
                                                  int N, int K) {
    __shared__ u16 As[16384];   // 2 bufs x 8192 u16
    __shared__ u16 Bs[16384];
    const int tid = threadIdx.x;
    const int lane = tid & 63, w = tid >> 6;
    const int lr = lane & 15, lg = lane >> 4;
    const int wm = w >> 1, wn = w & 1;
    // XCD-aware bijective block swizzle (all grids here have nwg % 8 == 0)
    const int nbx = gridDim.x;
    const int nwg = gridDim.x * gridDim.y;
    int flat = blockIdx.y * nbx + blockIdx.x;
    flat = (flat & 7) * (nwg >> 3) + (flat >> 3);
    const int m0 = (flat / nbx) * 128, n0 = (flat % nbx) * 128;

    const int srow = tid >> 3;                 // 0..31
    const int sd   = (tid & 7) ^ (srow & 7);   // data chunk this thread fetches
    const int kofs = (sd & 3) * 8;
    const bf16_t* Asrc = (sd < 4) ? Ah : Al;
    const bf16_t* Bsrc = (sd < 4) ? Bh : Bl;
    const bf16_t* pa0 = Asrc + (size_t)(m0 + srow     ) * K + kofs;
    const bf16_t* pa1 = Asrc + (size_t)(m0 + srow + 32) * K + kofs;
    const bf16_t* pa2 = Asrc + (size_t)(m0 + srow + 64) * K + kofs;
    const bf16_t* pa3 = Asrc + (size_t)(m0 + srow + 96) * K + kofs;
    const bf16_t* pb0 = Bsrc + (size_t)(n0 + srow     ) * K + kofs;
    const bf16_t* pb1 = Bsrc + (size_t)(n0 + srow + 32) * K + kofs;
    const bf16_t* pb2 = Bsrc + (size_t)(n0 + srow + 64) * K + kofs;
    const bf16_t* pb3 = Bsrc + (size_t)(n0 + srow + 96) * K + kofs;
    char* dA = (char*)As + tid*16;
    char* dB = (char*)Bs + tid*16;
    const int ca = (lg ^ (lr & 7)) * 8;        // HI chunk slot (u16 offset in row)

    auto STG = [&](int bsel, int kk) {
        char* a_ = dA + bsel*16384;
        char* b_ = dB + bsel*16384;
        gll16(pa0 + kk, a_);          gll16(pa1 + kk, a_ + 4096);
        gll16(pa2 + kk, a_ + 8192);   gll16(pa3 + kk, a_ + 12288);
        gll16(pb0 + kk, b_);          gll16(pb1 + kk, b_ + 4096);
        gll16(pb2 + kk, b_ + 8192);   gll16(pb3 + kk, b_ + 12288);
    };

    STG(0, 0);
    asm volatile("s_waitcnt vmcnt(0)" ::: "memory");
    __syncthreads();
    f32x4 acc[4][4] = {};
    int cur = 0;
    for (int k0 = 0; k0 < K; k0 += 32) {
        if (k0 + 32 < K) STG(cur ^ 1, k0 + 32);
        const u16* Ab = As + cur*8192;
        const u16* Bb = Bs + cur*8192;
        bf16x8 ah[4], al[4], bh[4], bl[4];
        #pragma unroll
        for (int i = 0; i < 4; i++) {
            const int ao = (wm*64 + i*16 + lr)*64 + ca;
            const int bo = (wn*64 + i*16 + lr)*64 + ca;
            ah[i] = *(const bf16x8*)&Ab[ao];
            al[i] = *(const bf16x8*)&Ab[ao ^ 32];   // chunk c^4 = LO slot
            bh[i] = *(const bf16x8*)&Bb[bo];
            bl[i] = *(const bf16x8*)&Bb[bo ^ 32];
        }
        #pragma unroll
        for (int i = 0; i < 4; i++)
            #pragma unroll
            for (int j = 0; j < 4; j++) {
                acc[i][j] = mfma16(ah[i], bh[j], acc[i][j]);
                acc[i][j] = mfma16(ah[i], bl[j], acc[i][j]);
                acc[i][j] = mfma16(al[i], bh[j], acc[i][j]);
            }
        asm volatile("s_waitcnt vmcnt(0)" ::: "memory");
        __syncthreads();
        cur ^= 1;
    }
    #pragma unroll
    for (int i = 0; i < 4; i++) {
        #pragma unroll
        for (int j = 0; j < 4; j++) {
            const int row = m0 + wm*64 + i*16 + lg*4;
            const int col = n0 + wn*64 + j*16 + lr;
            const f32x4 v = acc[i][j];
            if (EPI == 1) {
                #pragma unroll
                for (int r = 0; r < 4; r++) {
                    const size_t o = (size_t)(row + r) * N + col;
                    C[o] = res[o] + v[r];
                }
            } else {
                if (col < QKN) {   // Q (scaled) or K
                    const float sc = (col < DEMB) ? 0.125f : 1.0f;
                    #pragma unroll
                    for (int r = 0; r < 4; r++) {
                        const size_t o = (size_t)(row + r) * QKN + col;
                        const float f = v[r] * sc;
                        const __bf16 hb = (__bf16)f;
                        qkh[o] = hb;
                        qkl[o] = (__bf16)(f - (float)hb);
                    }
                } else {           // V -> V^T [ (b*16+h)*64 + d ][ t ]
                    const int d = col - QKN;
                    const int hh = d >> 6, dd = d & 63;
                    const int bb = row >> 11, t = row & 2047;
                    const size_t base = ((size_t)(bb*16 + hh)*64 + dd) * TSEQ + t;
                    #pragma unroll
                    for (int r = 0; r < 4; r++) {
                        const float f = v[r];
                        const __bf16 hb = (__bf16)f;
                        vth[base + r] = hb;
                        vtl[base + r] = (__bf16)(f - (float)hb);
                    }
                }
            }
        }
    }
}

// ---------------- grouped per-expert bf16 GEMM (EPI 2: relu^2; EPI 3: plain) ----------
// 2-phase pipeline + packed row-pair LDS [64 rp][8 chunks x 16B], slot(rp,c) d=c^(rp&7).
template<int EPI, int GATHER>
__global__ __launch_bounds__(256) void gemm_moe(const bf16_t* __restrict__ A,
                                                const bf16_t* __restrict__ Ball,
                                                bf16_t* __restrict__ C,
                                                const int* __restrict__ rowmap,
                                                const int* __restrict__ counts,
                                                const int* __restrict__ offs,
                                                int N, int K) {
    const int e = blockIdx.z;
    const int cnt = counts[e];
    if ((int)blockIdx.y * 128 >= cnt) return;
    const int base = offs[e];
    const bf16_t* Bt = Ball + (size_t)e * N * K;
    __shared__ u16 As[8192];   // 2 bufs x 4096 u16
    __shared__ u16 Bs[8192];
    const int tid = threadIdx.x;
    const int lane = tid & 63, w = tid >> 6;
    const int lr = lane & 15, lg = lane >> 4;
    const int wm = w >> 1, wn = w & 1;
    const int m0 = blockIdx.y * 128, n0 = blockIdx.x * 128;

    const int srp = tid >> 3;                  // 0..31 (rowpair)
    const int sd  = (tid & 7) ^ (srp & 7);
    const int smrow = 2*srp + (sd >> 2);       // 0..63
    const int kofs  = (sd & 3) * 8;
    const int l0 = min(m0 + smrow, cnt - 1), l1 = min(m0 + 64 + smrow, cnt - 1);
    const size_t r0 = GATHER ? (size_t)rowmap[base + l0] : (size_t)(base + l0);
    const size_t r1 = GATHER ? (size_t)rowmap[base + l1] : (size_t)(base + l1);
    const bf16_t* pa0 = A + r0 * K + kofs;
    const bf16_t* pa1 = A + r1 * K + kofs;
    const bf16_t* pb0 = Bt + (size_t)(n0 + smrow)      * K + kofs;
    const bf16_t* pb1 = Bt + (size_t)(n0 + 64 + smrow) * K + kofs;
    char* dA = (char*)As + tid*16;
    char* dB = (char*)Bs + tid*16;
    const int cs = (((lr & 1) << 2) + lg) ^ ((lr >> 1) & 7);   // read chunk slot

    auto STG = [&](int bsel, int kk) {
        char* a_ = dA + bsel*8192;
        char* b_ = dB + bsel*8192;
        gll16(pa0 + kk, a_); gll16(pa1 + kk, a_ + 4096);
        gll16(pb0 + kk, b_); gll16(pb1 + kk, b_ + 4096);
    };

    STG(0, 0);
    asm volatile("s_waitcnt vmcnt(0)" ::: "memory");
    __syncthreads();
    f32x4 acc[4][4] = {};
    int cur = 0;
    for (int k0 = 0; k0 < K; k0 += 32) {
        if (k0 + 32 < K) STG(cur ^ 1, k0 + 32);
        const u16* Ab = As + cur*4096;
        const u16* Bb = Bs + cur*4096;
        bf16x8 af[4], bfr[4];
        #pragma unroll
        for (int i = 0; i < 4; i++) {
            af[i]  = *(const bf16x8*)&Ab[(wm*32 + i*8 + (lr>>1))*64 + cs*8];
            bfr[i] = *(const bf16x8*)&Bb[(wn*32 + i*8 + (lr>>1))*64 + cs*8];
        }
        #pragma unroll
        for (int i = 0; i < 4; i++)
            #pragma unroll
            for (int j = 0; j < 4; j++)
                acc[i][j] = mfma16(af[i], bfr[j], acc[i][j]);
        asm volatile("s_waitcnt vmcnt(0)" ::: "memory");
        __syncthreads();
        cur ^= 1;
    }
    #pragma unroll
    for (int i = 0; i < 4; i++) {
        #pragma unroll
        for (int j = 0; j < 4; j++) {
            const int rowl = m0 + wm*64 + i*16 + lg*4;
            const int col  = n0 + wn*64 + j*16 + lr;
            const f32x4 v = acc[i][j];
            #pragma unroll
            for (int r = 0; r < 4; r++) {
                if (rowl + r < cnt) {
                    float xv = v[r];
                    if (EPI == 2) { xv = fmaxf(xv, 0.f); xv = xv * xv; }
                    C[(size_t)(base + rowl + r) * N + col] = (__bf16)xv;
                }
            }
        }
    }
}

// ---------------- split-bf16 MFMA flash attention, causal, balanced pairs ----------------
// grid (16,16,2) with XCD-chunked remap: each XCD owns 4 full (b,h) groups -> K/V L2-local.
// block handles q-tiles qa and 31-qa (64 rows each) in ONE kv sweep; 4 waves x 16 q-rows.
__global__ __launch_bounds__(256) void attn_mfma(const bf16_t* __restrict__ qkh,
                                                 const bf16_t* __restrict__ qkl,
                                                 const bf16_t* __restrict__ vth,
                                                 const bf16_t* __restrict__ vtl,
                                                 bf16_t* __restrict__ aoh,
                                                 bf16_t* __restrict__ aol) {
    __shared__ u16 KsH[64*64];   // [kv][d], chunk-swizzled c^=kv&7
    __shared__ u16 KsL[64*64];
    __shared__ u16 VtH[64*64];   // [d][kv], chunk-swizzled c^=d&7 (src pre-swizzled)
    __shared__ u16 VtL[64*64];
    __shared__ u16 P_H[4*16*72]; // per-wave P / output bounce
    __shared__ u16 P_L[4*16*72];
    const int tid = threadIdx.x, lane = tid & 63, wv = tid >> 6;
    const int lr = lane & 15, lg = lane >> 4;
    // XCD-chunked bijective remap (512 blocks, 512%8==0): XCD c gets swz in [c*64, c*64+64)
    const int L = blockIdx.x + blockIdx.y*16 + blockIdx.z*256;
    const int swz = (L & 7)*64 + (L >> 3);
    const int qa = swz & 15;
    const int h  = (swz >> 4) & 15;
    const int b  = swz >> 8;
    const int qb = 31 - qa;
    u16* plwH = P_H + wv * 16 * 72;
    u16* plwL = P_L + wv * 16 * 72;
    const int wq0A = qa*64 + wv*16;
    const int wq0B = qb*64 + wv*16;

    bf16x8 qAh[2], qAl[2], qBh[2], qBl[2];
    #pragma unroll
    for (int kf = 0; kf < 2; kf++) {
        const size_t qoA = (size_t)(b*TSEQ + wq0A + lr)*QKN + h*64 + kf*32 + lg*8;
        const size_t qoB = (size_t)(b*TSEQ + wq0B + lr)*QKN + h*64 + kf*32 + lg*8;
        qAh[kf] = *(const bf16x8*)(qkh + qoA);
        qAl[kf] = *(const bf16x8*)(qkl + qoA);
        qBh[kf] = *(const bf16x8*)(qkh + qoB);
        qBl[kf] = *(const bf16x8*)(qkl + qoB);
    }

    f32x4 ofA[4] = {}, ofB[4] = {};
    float mA = -1e30f, lA = 0.f, mB = -1e30f, lB = 0.f;

    const int skv = tid >> 3;                 // 0..31
    const int pst = tid & 7;
    const int chs = pst ^ (skv & 7);          // swizzled source chunk (K and V^T alike)
    const int bh = b*16 + h;
    const bf16_t* kh = qkh + 1024;
    const bf16_t* kl = qkl + 1024;
    const size_t vrow0 = (size_t)(bh*64 + skv)      * TSEQ;
    const size_t vrow1 = (size_t)(bh*64 + skv + 32) * TSEQ;

    auto step = [&](f32x4 (&of)[4], float& mrun, float& lrun,
                    const bf16x8 (&qfh)[2], const bf16x8 (&qfl)[2],
                    const int wq0, const bool diag, const int kvb) {
        f32x4 sf[4] = {};
        #pragma unroll
        for (int kf = 0; kf < 2; kf++)
            #pragma unroll
            for (int f = 0; f < 4; f++) {
                const int idx = (f*16 + lr)*64 + ((kf*32 + lg*8) ^ ((lr & 7) << 3));
                const bf16x8 ah = *(const bf16x8*)&KsH[idx];
                const bf16x8 al = *(const bf16x8*)&KsL[idx];
                sf[f] = mfma16(ah, qfh[kf], sf[f]);
                sf[f] = mfma16(ah, qfl[kf], sf[f]);
                sf[f] = mfma16(al, qfh[kf], sf[f]);
            }
        if (diag) {
            #pragma unroll
            for (int f = 0; f < 4; f++)
                #pragma unroll
                for (int r = 0; r < 4; r++)
                    if (kvb + f*16 + lg*4 + r > wq0 + lr) sf[f][r] = -1e30f;
        }
        float tm = -1e30f;
        #pragma unroll
        for (int f = 0; f < 4; f++)
            tm = fmaxf(tm, fmaxf(fmaxf(sf[f][0], sf[f][1]), fmaxf(sf[f][2], sf[f][3])));
        tm = fmaxf(tm, __shfl_xor(tm, 16));
        tm = fmaxf(tm, __shfl_xor(tm, 32));
        const float mnew = fmaxf(mrun, tm);
        const float fac = __expf(mrun - mnew);
        mrun = mnew;
        float ps = 0.f;
        #pragma unroll
        for (int f = 0; f < 4; f++) {
            float p[4];
            #pragma unroll
            for (int r = 0; r < 4; r++) { p[r] = __expf(sf[f][r] - mnew); ps += p[r]; }
            u16 hb4[4], lb4[4];
            #pragma unroll
            for (int r = 0; r < 4; r++) {
                const __bf16 hb = (__bf16)p[r];
                hb4[r] = f2bf(p[r]);
                lb4[r] = f2bf(p[r] - (float)hb);
            }
            u32* pwh = (u32*)&plwH[lr*72 + f*16 + lg*4];
            u32* pwl = (u32*)&plwL[lr*72 + f*16 + lg*4];
            pwh[0] = (u32)hb4[0] | ((u32)hb4[1] << 16);
            pwh[1] = (u32)hb4[2] | ((u32)hb4[3] << 16);
            pwl[0] = (u32)lb4[0] | ((u32)lb4[1] << 16);
            pwl[1] = (u32)lb4[2] | ((u32)lb4[3] << 16);
        }
        ps += __shfl_xor(ps, 16);
        ps += __shfl_xor(ps, 32);
        lrun = lrun*fac + ps;
        #pragma unroll
        for (int f2 = 0; f2 < 4; f2++)
            #pragma unroll
            for (int r = 0; r < 4; r++) of[f2][r] *= fac;
        #pragma unroll
        for (int hf = 0; hf < 2; hf++) {
            const bf16x8 pbh = *(const bf16x8*)&plwH[lr*72 + hf*32 + lg*8];
            const bf16x8 pbl = *(const bf16x8*)&plwL[lr*72 + hf*32 + lg*8];
            #pragma unroll
            for (int f2 = 0; f2 < 4; f2++) {
                const int vidx = (f2*16 + lr)*64 + (((hf*4 + lg) ^ (lr & 7)) << 3);
                const bf16x8 vah = *(const bf16x8*)&VtH[vidx];
                const bf16x8 val = *(const bf16x8*)&VtL[vidx];
                of[f2] = mfma16(vah, pbh, of[f2]);
                of[f2] = mfma16(vah, pbl, of[f2]);
                of[f2] = mfma16(val, pbh, of[f2]);
            }
        }
    };

    for (int kt = 0; kt <= qb; kt++) {
        __syncthreads();
        const size_t krow = (size_t)(b*TSEQ + kt*64 + skv)*QKN + h*64;
        gll16(kh + krow + chs*8,                     (char*)KsH + tid*16);
        gll16(kh + krow + (size_t)32*QKN + chs*8,    (char*)KsH + 4096 + tid*16);
        gll16(kl + krow + chs*8,                     (char*)KsL + tid*16);
        gll16(kl + krow + (size_t)32*QKN + chs*8,    (char*)KsL + 4096 + tid*16);
        gll16(vth + vrow0 + kt*64 + chs*8,           (char*)VtH + tid*16);
        gll16(vth + vrow1 + kt*64 + chs*8,           (char*)VtH + 4096 + tid*16);
        gll16(vtl + vrow0 + kt*64 + chs*8,           (char*)VtL + tid*16);
        gll16(vtl + vrow1 + kt*64 + chs*8,           (char*)VtL + 4096 + tid*16);
        __syncthreads();
        if (kt <= qa) step(ofA, mA, lA, qAh, qAl, wq0A, kt == qa, kt*64);
        step(ofB, mB, lB, qBh, qBl, wq0B, kt == qb, kt*64);
    }

    // epilogue per tile: normalize, split, bounce through per-wave LDS, coalesced store
    const float invA = 1.f / lA, invB = 1.f / lB;
    #pragma unroll
    for (int f2 = 0; f2 < 4; f2++) {
        u16 hb4[4], lb4[4];
        #pragma unroll
        for (int r = 0; r < 4; r++) {
            const float f = ofA[f2][r] * invA;
            const __bf16 hb = (__bf16)f;
            hb4[r] = f2bf(f);
            lb4[r] = f2bf(f - (float)hb);
        }
        u32* pwh = (u32*)&plwH[lr*72 + f2*16 + lg*4];
        u32* pwl = (u32*)&plwL[lr*72 + f2*16 + lg*4];
        pwh[0] = (u32)hb4[0] | ((u32)hb4[1] << 16);
        pwh[1] = (u32)hb4[2] | ((u32)hb4[3] << 16);
        pwl[0] = (u32)lb4[0] | ((u32)lb4[1] << 16);
        pwl[1] = (u32)lb4[2] | ((u32)lb4[3] << 16);
    }
    asm volatile("s_waitcnt lgkmcnt(0)" ::: "memory");
    __builtin_amdgcn_sched_barrier(0);
    #pragma unroll
    for (int pass = 0; pass < 2; pass++) {
        const int qlr = pass*8 + (lane >> 3);
        const int ch = (lane & 7) * 8;
        const bf16x8 oh = *(const bf16x8*)&plwH[qlr*72 + ch];
        const bf16x8 ol = *(const bf16x8*)&plwL[qlr*72 + ch];
        const size_t go = (size_t)(b*TSEQ + wq0A + qlr) * DEMB + h*64 + ch;
        *(bf16x8*)(aoh + go) = oh;
        *(bf16x8*)(aol + go) = ol;
    }
    asm volatile("s_waitcnt lgkmcnt(0)" ::: "memory");
    __builtin_amdgcn_sched_barrier(0);
    #pragma unroll
    for (int f2 = 0; f2 < 4; f2++) {
        u16 hb4[4], lb4[4];
        #pragma unroll
        for (int r = 0; r < 4; r++) {
            const float f = ofB[f2][r] * invB;
            const __bf16 hb = (__bf16)f;
            hb4[r] = f2bf(f);
            lb4[r] = f2bf(f - (float)hb);
        }
        u32* pwh = (u32*)&plwH[lr*72 + f2*16 + lg*4];
        u32* pwl = (u32*)&plwL[lr*72 + f2*16 + lg*4];
        pwh[0] = (u32)hb4[0] | ((u32)hb4[1] << 16);
        pwh[1] = (u32)hb4[2] | ((u32)hb4[3] << 16);
        pwl[0] = (u32)lb4[0] | ((u32)lb4[1] << 16);
        pwl[1] = (u32)lb4[2] | ((u32)lb4[3] << 16);
    }
    asm volatile("s_waitcnt lgkmcnt(0)" ::: "memory");
    __builtin_amdgcn_sched_barrier(0);
    #pragma unroll
    for (int pass = 0; pass < 2; pass++) {
        const int qlr = pass*8 + (lane >> 3);
        const int ch = (lane & 7) * 8;
        const bf16x8 oh = *(const bf16x8*)&plwH[qlr*72 + ch];
        const bf16x8 ol = *(const bf16x8*)&plwL[qlr*72 + ch];
        const size_t go = (size_t)(b*TSEQ + wq0B + qlr) * DEMB + h*64 + ch;
        *(bf16x8*)(aoh + go) = oh;
        *(bf16x8*)(aol + go) = ol;
    }
}

// ---------------- MoE routing (fp32, rmsnorm folded in) ----------------
__global__ void zero8(int* c) { if (threadIdx.x < NEXP) c[threadIdx.x] = 0; }

__global__ __launch_bounds__(256) void router_k(const float* __restrict__ xout,
                                                const float* __restrict__ rw,
                                                int* __restrict__ idx,
                                                float* __restrict__ wts,
                                                int* __restrict__ pos,
                                                int* __restrict__ counts) {
    const int tok = blockIdx.x * 4 + (threadIdx.x >> 6);
    const int lane = threadIdx.x & 63;
    const float* xr = xout + (size_t)tok * DEMB;
    float ss = 0.f;
    float acc[NEXP];
    #pragma unroll
    for (int e = 0; e < NEXP; e++) acc[e] = 0.f;
    for (int kk = lane; kk < DEMB; kk += 64) {
        const float xv = xr[kk];
        ss += xv * xv;
        #pragma unroll
        for (int e = 0; e < NEXP; e++) acc[e] += xv * rw[kk*NEXP + e];
    }
    #pragma unroll
    for (int off = 32; off; off >>= 1) ss += __shfl_xor(ss, off);
    #pragma unroll
    for (int e = 0; e < NEXP; e++) {
        #pragma unroll
        for (int off = 32; off; off >>= 1) acc[e] += __shfl_xor(acc[e], off);
    }
    if (lane == 0) {
        const float r = rsqrtf(ss * (1.0f/DEMB) + 1e-5f);
        float v[NEXP];
        #pragma unroll
        for (int e = 0; e < NEXP; e++) v[e] = acc[e] * r;
        int b0 = 0; float v0 = v[0];
        #pragma unroll
        for (int e = 1; e < NEXP; e++) if (v[e] > v0) { v0 = v[e]; b0 = e; }
        int b1 = -1; float v1 = -1e30f;
        #pragma unroll
        for (int e = 0; e < NEXP; e++) if (e != b0 && v[e] > v1) { v1 = v[e]; b1 = e; }
        const float w0 = 1.f / (1.f + __expf(v1 - v0));
        idx[tok*2+0] = b0; idx[tok*2+1] = b1;
        wts[tok*2+0] = w0; wts[tok*2+1] = 1.f - w0;
        pos[tok*2+0] = atomicAdd(&counts[b0], 1);
        pos[tok*2+1] = atomicAdd(&counts[b1], 1);
    }
}

__global__ void offsets_k(const int* __restrict__ counts, int* __restrict__ offs) {
    if (threadIdx.x == 0) {
        int s = 0;
        for (int e = 0; e < NEXP; e++) { offs[e] = s; s += counts[e]; }
    }
}

__global__ __launch_bounds__(256) void buildmap_k(const int* __restrict__ idx,
                                                  const int* __restrict__ pos,
                                                  const int* __restrict__ offs,
                                                  int* __restrict__ rowmap,
                                                  int* __restrict__ rowpos) {
    const int n = blockIdx.x * 256 + threadIdx.x;
    #pragma unroll
    for (int s = 0; s < 2; s++) {
        const int e = idx[n*2+s];
        const int r = offs[e] + pos[n*2+s];
        rowmap[r] = n;
        rowpos[n*2+s] = r;
    }
}

__global__ __launch_bounds__(256) void combine_k(const bf16_t* __restrict__ oe,
                                                 const int* __restrict__ rowpos,
                                                 const float* __restrict__ wts,
                                                 float* __restrict__ out) {
    const int n = blockIdx.x;
    const int r0 = rowpos[n*2+0], r1 = rowpos[n*2+1];
    const float w0 = wts[n*2+0], w1 = wts[n*2+1];
    const int c = threadIdx.x * 4;
    const bf16x4 a  = *(const bf16x4*)(oe + (size_t)r0*DEMB + c);
    const bf16x4 b4 = *(const bf16x4*)(oe + (size_t)r1*DEMB + c);
    float4* op = (float4*)(out + (size_t)n*DEMB + c);
    float4 o = *op;
    o.x += w0*(float)a[0] + w1*(float)b4[0];
    o.y += w0*(float)a[1] + w1*(float)b4[1];
    o.z += w0*(float)a[2] + w1*(float)b4[2];
    o.w += w0*(float)a[3] + w1*(float)b4[3];
    *op = o;
}

extern "C" void kernel_launch(void* const* d_in, const int* in_sizes, int n_in,
                              void* d_out, int out_size, void* d_ws, size_t ws_size,
                              hipStream_t stream) {
    (void)in_sizes; (void)n_in; (void)out_size; (void)ws_size;
    const float* x   = (const float*)d_in[0];
    const float* wq  = (const float*)d_in[1];
    const float* wk  = (const float*)d_in[2];
    const float* wv  = (const float*)d_in[3];
    const float* wo  = (const float*)d_in[4];
    const float* rw  = (const float*)d_in[5];
    const float* fc1 = (const float*)d_in[6];
    const float* fc2 = (const float*)d_in[7];
    float* out = (float*)d_out;
    char* ws = (char*)d_ws;
    const size_t MB = 1024*1024;

    bf16_t* wqkv_h = (bf16_t*)(ws);
    bf16_t* wqkv_l = (bf16_t*)(ws + 6*MB);
    bf16_t* wo_h   = (bf16_t*)(ws + 12*MB);
    bf16_t* wo_l   = (bf16_t*)(ws + 14*MB);
    bf16_t* qk_h   = (bf16_t*)(ws + 16*MB);
    bf16_t* qk_l   = (bf16_t*)(ws + 32*MB);
    bf16_t* vt_h   = (bf16_t*)(ws + 48*MB);
    bf16_t* vt_l   = (bf16_t*)(ws + 56*MB);
    bf16_t* fc1_t  = (bf16_t*)(ws + 16*MB);
    bf16_t* fc2_t  = (bf16_t*)(ws + 48*MB);
    bf16_t* h_hi   = (bf16_t*)(ws + 64*MB);
    bf16_t* h_lo   = (bf16_t*)(ws + 72*MB);
    bf16_t* ao_h   = (bf16_t*)(ws + 64*MB);
    bf16_t* ao_l   = (bf16_t*)(ws + 72*MB);
    bf16_t* h      = (bf16_t*)(ws + 80*MB);
    bf16_t* h1     = (bf16_t*)(ws + 88*MB);
    bf16_t* oe     = (bf16_t*)(ws);
    char* meta = ws + 120*MB;
    int*   idx    = (int*)(meta);
    int*   pos    = (int*)(meta + 64*1024);
    int*   rowmap = (int*)(meta + 128*1024);
    int*   rowpos = (int*)(meta + 192*1024);
    float* wts    = (float*)(meta + 256*1024);
    int*   counts = (int*)(meta + 320*1024);
    int*   offs   = (int*)(meta + 320*1024 + 256);

    const dim3 blk(256);

    // ---- attention path ----
    transp_split_k<<<dim3(32,32), blk, 0, stream>>>(wq, wqkv_h,               wqkv_l,               1024, 1024);
    transp_split_k<<<dim3(32,32), blk, 0, stream>>>(wk, wqkv_h + 1024*1024,   wqkv_l + 1024*1024,   1024, 1024);
    transp_split_k<<<dim3(32,32), blk, 0, stream>>>(wv, wqkv_h + 2*1024*1024, wqkv_l + 2*1024*1024, 1024, 1024);
    transp_split_k<<<dim3(32,32), blk, 0, stream>>>(wo, wo_h,                 wo_l,                 1024, 1024);
    rmsnorm_split_k<<<NTOK, blk, 0, stream>>>(x, h_hi, h_lo);
    gemm_split<3><<<dim3(QKVS/128, NTOK/128), blk, 0, stream>>>(
        h_hi, h_lo, wqkv_h, wqkv_l, nullptr, nullptr, qk_h, qk_l, vt_h, vt_l, QKVS, 1024);
    attn_mfma<<<dim3(16, 16, 2), blk, 0, stream>>>(qk_h, qk_l, vt_h, vt_l, ao_h, ao_l);
    gemm_split<1><<<dim3(DEMB/128, NTOK/128), blk, 0, stream>>>(
        ao_h, ao_l, wo_h, wo_l, x, out, nullptr, nullptr, nullptr, nullptr, DEMB, 1024);

    // ---- MoE path (fp32 router, bf16 experts) ----
    transp_k<<<dim3(64,32,8), blk, 0, stream>>>(fc1, fc1_t, 1024, 2048);
    transp_k<<<dim3(32,64,8), blk, 0, stream>>>(fc2, fc2_t, 2048, 1024);
    rmsnorm_bf_k<<<NTOK, blk, 0, stream>>>(out, h);
    zero8<<<1, 64, 0, stream>>>(counts);
    router_k<<<NTOK/4, blk, 0, stream>>>(out, rw, idx, wts, pos, counts);
    offsets_k<<<1, 64, 0, stream>>>(counts, offs);
    buildmap_k<<<NTOK/256, blk, 0, stream>>>(idx, pos, offs, rowmap, rowpos);
    gemm_moe<2,1><<<dim3(EDIM/128, 32, NEXP), blk, 0, stream>>>(
        h, fc1_t, h1, rowmap, counts, offs, EDIM, 1024);
    gemm_moe<3,0><<<dim3(DEMB/128, 32, NEXP), blk, 0, stream>>>(
        h1, fc2_t, oe, rowmap, counts, offs, DEMB, EDIM);
    combine_k<<<NTOK, blk, 0, stream>>>(oe, rowpos, wts, out);
}

// Round 10
// 507.914 us; speedup vs baseline: 1.0865x; 1.0356x over previous
//
#include <hip/hip_runtime.h>
#include <math.h>

#define NTOK 4096
#define DEMB 1024
#define TSEQ 2048
#define QKVS 3072
#define QKN  2048
#define EDIM 2048
#define NEXP 8

typedef unsigned short u16;
typedef unsigned int u32;
typedef __bf16 bf16_t;
typedef __bf16 bf16x8 __attribute__((ext_vector_type(8)));
typedef __bf16 bf16x4 __attribute__((ext_vector_type(4)));
typedef float f32x4 __attribute__((ext_vector_type(4)));

__device__ __forceinline__ f32x4 mfma16(bf16x8 a, bf16x8 b, f32x4 c) {
    return __builtin_amdgcn_mfma_f32_16x16x32_bf16(a, b, c, 0, 0, 0);
}
__device__ __forceinline__ void gll16(const void* g, void* l) {
    __builtin_amdgcn_global_load_lds((const __attribute__((address_space(1))) u32*)g,
                                     (__attribute__((address_space(3))) u32*)l, 16, 0, 0);
}
__device__ __forceinline__ u16 f2bf(float x) {
    union { __bf16 h; u16 u; } c; c.h = (__bf16)x; return c.u;
}

// ---------------- rmsnorm fp32 -> split bf16 (hi, lo) ----------------
__global__ __launch_bounds__(256) void rmsnorm_split_k(const float* __restrict__ x,
                                                       bf16_t* __restrict__ hi,
                                                       bf16_t* __restrict__ lo) {
    const int row = blockIdx.x;
    const float4 v = ((const float4*)(x + (size_t)row * DEMB))[threadIdx.x];
    float ss = v.x*v.x + v.y*v.y + v.z*v.z + v.w*v.w;
    #pragma unroll
    for (int off = 32; off; off >>= 1) ss += __shfl_xor(ss, off);
    __shared__ float wsum[4];
    if ((threadIdx.x & 63) == 0) wsum[threadIdx.x >> 6] = ss;
    __syncthreads();
    const float r = rsqrtf((wsum[0]+wsum[1]+wsum[2]+wsum[3]) * (1.0f/DEMB) + 1e-5f);
    const float f[4] = {v.x*r, v.y*r, v.z*r, v.w*r};
    bf16x4 hv, lv;
    #pragma unroll
    for (int j = 0; j < 4; j++) {
        const __bf16 hb = (__bf16)f[j];
        hv[j] = hb;
        lv[j] = (__bf16)(f[j] - (float)hb);
    }
    ((bf16x4*)(hi + (size_t)row*DEMB))[threadIdx.x] = hv;
    ((bf16x4*)(lo + (size_t)row*DEMB))[threadIdx.x] = lv;
}

// ---------------- weight transpose fp32 [K][M] -> split bf16 [M][K] ----------------
__global__ __launch_bounds__(256) void transp_split_k(const float* __restrict__ w,
                                                      bf16_t* __restrict__ wth,
                                                      bf16_t* __restrict__ wtl,
                                                      int K, int M) {
    __shared__ float t[32][33];
    const int m0 = blockIdx.x*32, k0 = blockIdx.y*32;
    const int tx = threadIdx.x & 31, ty = threadIdx.x >> 5;
    #pragma unroll
    for (int i = 0; i < 32; i += 8) t[ty+i][tx] = w[(size_t)(k0+ty+i)*M + m0+tx];
    __syncthreads();
    #pragma unroll
    for (int i = 0; i < 32; i += 8) {
        const float f = t[tx][ty+i];
        const __bf16 hb = (__bf16)f;
        wth[(size_t)(m0+ty+i)*K + k0+tx] = hb;
        wtl[(size_t)(m0+ty+i)*K + k0+tx] = (__bf16)(f - (float)hb);
    }
}

// ---------------- weight transpose fp32 [K][M] -> plain bf16 [M][K] (per expert) ------
__global__ __launch_bounds__(256) void transp_k(const float* __restrict__ w,
                                                bf16_t* __restrict__ wt,
                                                int K, int M) {
    __shared__ float t[32][33];
    const size_t eo = (size_t)blockIdx.z * K * M;
    w += eo; wt += eo;
    const int m0 = blockIdx.x*32, k0 = blockIdx.y*32;
    const int tx = threadIdx.x & 31, ty = threadIdx.x >> 5;
    #pragma unroll
    for (int i = 0; i < 32; i += 8) t[ty+i][tx] = w[(size_t)(k0+ty+i)*M + m0+tx];
    __syncthreads();
    #pragma unroll
    for (int i = 0; i < 32; i += 8) wt[(size_t)(m0+ty+i)*K + k0+tx] = (__bf16)t[tx][ty+i];
}

// ---------------- QKV split-bf16 GEMM, 256x256 tile, 8 waves, 2-phase/K-tile ----------
// LDS: per buf, A [256 rows][8 chunk-slots x 16B] packed HI|LO, slot(row,c) = chunk c^(row&7)
// (chunk d<4 -> HI k-chunk d, d>=4 -> LO). Double-buffered: 128 KB total.
// Wave grid 2M x 4N, wave tile 128x64: B frags register-resident per K-tile (4:1 MFMA:ds_read).
// Raw s_barrier + explicit waitcnt (no __syncthreads drain in loop).
__global__ __launch_bounds__(512) void gemm_qkv256(const bf16_t* __restrict__ Ah,
                                                   const bf16_t* __restrict__ Al,
                                                   const bf16_t* __restrict__ Bh,
                                                   const bf16_t* __restrict__ Bl,
                                                   bf16_t* __restrict__ qkh,
                                                   bf16_t* __restrict__ qkl,
                                                   bf16_t* __restrict__ vth,
                                                   bf16_t* __restrict__ vtl) {
    __shared__ u16 As[2*16384];
    __shared__ u16 Bs[2*16384];
    const int tid = threadIdx.x;
    const int lane = tid & 63, w = tid >> 6;
    const int lr = lane & 15, lg = lane >> 4;
    const int wm = w >> 2, wn = w & 3;
    // XCD-aware bijective swizzle: 192 blocks, 192 % 8 == 0
    int flat = blockIdx.y * 12 + blockIdx.x;
    flat = (flat & 7) * 24 + (flat >> 3);
    const int m0 = (flat / 12) * 256, n0 = (flat % 12) * 256;

    const int srow = tid >> 3;                 // 0..63
    const int sd   = (tid & 7) ^ (srow & 7);
    const int kofs = (sd & 3) * 8;
    const bf16_t* Asrc = (sd < 4) ? Ah : Al;
    const bf16_t* Bsrc = (sd < 4) ? Bh : Bl;
    const bf16_t* pA0 = Asrc + (size_t)(m0 + srow      ) * 1024 + kofs;
    const bf16_t* pA1 = Asrc + (size_t)(m0 + srow +  64) * 1024 + kofs;
    const bf16_t* pA2 = Asrc + (size_t)(m0 + srow + 128) * 1024 + kofs;
    const bf16_t* pA3 = Asrc + (size_t)(m0 + srow + 192) * 1024 + kofs;
    const bf16_t* pB0 = Bsrc + (size_t)(n0 + srow      ) * 1024 + kofs;
    const bf16_t* pB1 = Bsrc + (size_t)(n0 + srow +  64) * 1024 + kofs;
    const bf16_t* pB2 = Bsrc + (size_t)(n0 + srow + 128) * 1024 + kofs;
    const bf16_t* pB3 = Bsrc + (size_t)(n0 + srow + 192) * 1024 + kofs;
    const int ca = (lg ^ (lr & 7)) * 8;

#define STG_Q(u_, kn_, nb_) do { \
    gll16(pA##u_ + (kn_), (char*)As + (nb_)*32768 + (u_)*8192 + tid*16); \
    gll16(pB##u_ + (kn_), (char*)Bs + (nb_)*32768 + (u_)*8192 + tid*16); } while (0)

    // prologue: stage tile 0 into buf 0
    STG_Q(0, 0, 0); STG_Q(1, 0, 0); STG_Q(2, 0, 0); STG_Q(3, 0, 0);
    asm volatile("s_waitcnt vmcnt(0)" ::: "memory");
    __builtin_amdgcn_sched_barrier(0);
    __syncthreads();

    f32x4 acc[8][4] = {};
    int cur = 0;
    for (int t = 0; t < 32; t++) {
        const u16* Ab = As + cur*16384;
        const u16* Bb = Bs + cur*16384;
        const int nb = cur ^ 1;
        const int kn = (t + 1) * 32;
        const bool more = (t < 31);

        // B frags for this K-tile (register-resident across both phases)
        bf16x8 bh[4], bl[4];
        #pragma unroll
        for (int j = 0; j < 4; j++) {
            const int bo = (wn*64 + j*16 + lr)*64 + ca;
            bh[j] = *(const bf16x8*)&Bb[bo];
            bl[j] = *(const bf16x8*)&Bb[bo ^ 32];
        }
        // ---- phase 0: A rows wm*128 + [0,64) ----
        {
            bf16x8 ah[4], al[4];
            #pragma unroll
            for (int i = 0; i < 4; i++) {
                const int ao = (wm*128 + i*16 + lr)*64 + ca;
                ah[i] = *(const bf16x8*)&Ab[ao];
                al[i] = *(const bf16x8*)&Ab[ao ^ 32];
            }
            if (more) { STG_Q(0, kn, nb); STG_Q(1, kn, nb); }
            __builtin_amdgcn_s_barrier();
            asm volatile("s_waitcnt lgkmcnt(0)" ::: "memory");
            __builtin_amdgcn_sched_barrier(0);
            __builtin_amdgcn_s_setprio(1);
            #pragma unroll
            for (int i = 0; i < 4; i++)
                #pragma unroll
                for (int j = 0; j < 4; j++) {
                    acc[i][j] = mfma16(ah[i], bh[j], acc[i][j]);
                    acc[i][j] = mfma16(ah[i], bl[j], acc[i][j]);
                    acc[i][j] = mfma16(al[i], bh[j], acc[i][j]);
                }
            __builtin_amdgcn_s_setprio(0);
            __builtin_amdgcn_s_barrier();
        }
        // ---- phase 1: A rows wm*128 + [64,128) ----
        {
            bf16x8 ah[4], al[4];
            #pragma unroll
            for (int i = 0; i < 4; i++) {
                const int ao = (wm*128 + 64 + i*16 + lr)*64 + ca;
                ah[i] = *(const bf16x8*)&Ab[ao];
                al[i] = *(const bf16x8*)&Ab[ao ^ 32];
            }
            if (more) { STG_Q(2, kn, nb); STG_Q(3, kn, nb); }
            __builtin_amdgcn_s_barrier();
            asm volatile("s_waitcnt lgkmcnt(0)" ::: "memory");
            __builtin_amdgcn_sched_barrier(0);
            __builtin_amdgcn_s_setprio(1);
            #pragma unroll
            for (int i = 0; i < 4; i++)
                #pragma unroll
                for (int j = 0; j < 4; j++) {
                    acc[4+i][j] = mfma16(ah[i], bh[j], acc[4+i][j]);
                    acc[4+i][j] = mfma16(ah[i], bl[j], acc[4+i][j]);
                    acc[4+i][j] = mfma16(al[i], bh[j], acc[4+i][j]);
                }
            __builtin_amdgcn_s_setprio(0);
            asm volatile("s_waitcnt vmcnt(0)" ::: "memory");
            __builtin_amdgcn_sched_barrier(0);
            __builtin_amdgcn_s_barrier();
        }
        cur ^= 1;
    }
#undef STG_Q
    // epilogue: Q (x0.125) / K -> qk split; V -> V^T split
    #pragma unroll
    for (int i = 0; i < 8; i++) {
        #pragma unroll
        for (int j = 0; j < 4; j++) {
            const int row = m0 + wm*128 + i*16 + lg*4;
            const int col = n0 + wn*64 + j*16 + lr;
            const f32x4 v = acc[i][j];
            if (col < QKN) {
                const float sc = (col < DEMB) ? 0.125f : 1.0f;
                #pragma unroll
                for (int r = 0; r < 4; r++) {
                    const size_t o = (size_t)(row + r) * QKN + col;
                    const float f = v[r] * sc;
                    const __bf16 hb = (__bf16)f;
                    qkh[o] = hb;
                    qkl[o] = (__bf16)(f - (float)hb);
                }
            } else {
                const int d = col - QKN;
                const int hh = d >> 6, dd = d & 63;
                const int bb = row >> 11, tt = row & 2047;
                const size_t base = ((size_t)(bb*16 + hh)*64 + dd) * TSEQ + tt;
                #pragma unroll
                for (int r = 0; r < 4; r++) {
                    const float f = v[r];
                    const __bf16 hb = (__bf16)f;
                    vth[base + r] = hb;
                    vtl[base + r] = (__bf16)(f - (float)hb);
                }
            }
        }
    }
}

// ---------------- 128² split-bf16 GEMM (WO): 2-phase dbuf, packed HI|LO rows ----------
template<int EPI>
__global__ __launch_bounds__(256) void gemm_split(const bf16_t* __restrict__ Ah,
                                                  const bf16_t* __restrict__ Al,
                                                  const bf16_t* __restrict__ Bh,
                                                  const bf16_t* __restrict__ Bl,
                                                  const float* __restrict__ res,
                                                  float* __restrict__ C,
                                                  int N, int K) {
    __shared__ u16 As[16384];
    __shared__ u16 Bs[16384];
    const int tid = threadIdx.x;
    const int lane = tid & 63, w = tid >> 6;
    const int lr = lane & 15, lg = lane >> 4;
    const int wm = w >> 1, wn = w & 1;
    const int nbx = gridDim.x;
    const int nwg = gridDim.x * gridDim.y;
    int flat = blockIdx.y * nbx + blockIdx.x;
    flat = (flat & 7) * (nwg >> 3) + (flat >> 3);
    const int m0 = (flat / nbx) * 128, n0 = (flat % nbx) * 128;

    const int srow = tid >> 3;
    const int sd   = (tid & 7) ^ (srow & 7);
    const int kofs = (sd & 3) * 8;
    const bf16_t* Asrc = (sd < 4) ? Ah : Al;
    const bf16_t* Bsrc = (sd < 4) ? Bh : Bl;
    const bf16_t* pa0 = Asrc + (size_t)(m0 + srow     ) * K + kofs;
    const bf16_t* pa1 = Asrc + (size_t)(m0 + srow + 32) * K + kofs;
    const bf16_t* pa2 = Asrc + (size_t)(m0 + srow + 64) * K + kofs;
    const bf16_t* pa3 = Asrc + (size_t)(m0 + srow + 96) * K + kofs;
    const bf16_t* pb0 = Bsrc + (size_t)(n0 + srow     ) * K + kofs;
    const bf16_t* pb1 = Bsrc + (size_t)(n0 + srow + 32) * K + kofs;
    const bf16_t* pb2 = Bsrc + (size_t)(n0 + srow + 64) * K + kofs;
    const bf16_t* pb3 = Bsrc + (size_t)(n0 + srow + 96) * K + kofs;
    char* dA = (char*)As + tid*16;
    char* dB = (char*)Bs + tid*16;
    const int ca = (lg ^ (lr & 7)) * 8;

    auto STG = [&](int bsel, int kk) {
        char* a_ = dA + bsel*16384;
        char* b_ = dB + bsel*16384;
        gll16(pa0 + kk, a_);          gll16(pa1 + kk, a_ + 4096);
        gll16(pa2 + kk, a_ + 8192);   gll16(pa3 + kk, a_ + 12288);
        gll16(pb0 + kk, b_);          gll16(pb1 + kk, b_ + 4096);
        gll16(pb2 + kk, b_ + 8192);   gll16(pb3 + kk, b_ + 12288);
    };

    STG(0, 0);
    asm volatile("s_waitcnt vmcnt(0)" ::: "memory");
    __syncthreads();
    f32x4 acc[4][4] = {};
    int cur = 0;
    for (int k0 = 0; k0 < K; k0 += 32) {
        if (k0 + 32 < K) STG(cur ^ 1, k0 + 32);
        const u16* Ab = As + cur*8192;
        const u16* Bb = Bs + cur*8192;
        bf16x8 ah[4], al[4], bh[4], bl[4];
        #pragma unroll
        for (int i = 0; i < 4; i++) {
            const int ao = (wm*64 + i*16 + lr)*64 + ca;
            const int bo = (wn*64 + i*16 + lr)*64 + ca;
            ah[i] = *(const bf16x8*)&Ab[ao];
            al[i] = *(const bf16x8*)&Ab[ao ^ 32];
            bh[i] = *(const bf16x8*)&Bb[bo];
            bl[i] = *(const bf16x8*)&Bb[bo ^ 32];
        }
        #pragma unroll
        for (int i = 0; i < 4; i++)
            #pragma unroll
            for (int j = 0; j < 4; j++) {
                acc[i][j] = mfma16(ah[i], bh[j], acc[i][j]);
                acc[i][j] = mfma16(ah[i], bl[j], acc[i][j]);
                acc[i][j] = mfma16(al[i], bh[j], acc[i][j]);
            }
        asm volatile("s_waitcnt vmcnt(0)" ::: "memory");
        __syncthreads();
        cur ^= 1;
    }
    #pragma unroll
    for (int i = 0; i < 4; i++) {
        #pragma unroll
        for (int j = 0; j < 4; j++) {
            const int row = m0 + wm*64 + i*16 + lg*4;
            const int col = n0 + wn*64 + j*16 + lr;
            const f32x4 v = acc[i][j];
            #pragma unroll
            for (int r = 0; r < 4; r++) {
                const size_t o = (size_t)(row + r) * N + col;
                C[o] = res[o] + v[r];
            }
        }
    }
}

// ---------------- grouped per-expert bf16 GEMM (EPI 2: relu^2; EPI 3: plain) ----------
template<int EPI, int GATHER>
__global__ __launch_bounds__(256) void gemm_moe(const bf16_t* __restrict__ A,
                                                const bf16_t* __restrict__ Ball,
                                                bf16_t* __restrict__ C,
                                                const int* __restrict__ rowmap,
                                                const int* __restrict__ counts,
                                                const int* __restrict__ offs,
                                                int N, int K) {
    const int e = blockIdx.z;
    const int cnt = counts[e];
    if ((int)blockIdx.y * 128 >= cnt) return;
    const int base = offs[e];
    const bf16_t* Bt = Ball + (size_t)e * N * K;
    __shared__ u16 As[8192];
    __shared__ u16 Bs[8192];
    const int tid = threadIdx.x;
    const int lane = tid & 63, w = tid >> 6;
    const int lr = lane & 15, lg = lane >> 4;
    const int wm = w >> 1, wn = w & 1;
    const int m0 = blockIdx.y * 128, n0 = blockIdx.x * 128;

    const int srp = tid >> 3;
    const int sd  = (tid & 7) ^ (srp & 7);
    const int smrow = 2*srp + (sd >> 2);
    const int kofs  = (sd & 3) * 8;
    const int l0 = min(m0 + smrow, cnt - 1), l1 = min(m0 + 64 + smrow, cnt - 1);
    const size_t r0 = GATHER ? (size_t)rowmap[base + l0] : (size_t)(base + l0);
    const size_t r1 = GATHER ? (size_t)rowmap[base + l1] : (size_t)(base + l1);
    const bf16_t* pa0 = A + r0 * K + kofs;
    const bf16_t* pa1 = A + r1 * K + kofs;
    const bf16_t* pb0 = Bt + (size_t)(n0 + smrow)      * K + kofs;
    const bf16_t* pb1 = Bt + (size_t)(n0 + 64 + smrow) * K + kofs;
    char* dA = (char*)As + tid*16;
    char* dB = (char*)Bs + tid*16;
    const int cs = (((lr & 1) << 2) + lg) ^ ((lr >> 1) & 7);

    auto STG = [&](int bsel, int kk) {
        char* a_ = dA + bsel*8192;
        char* b_ = dB + bsel*8192;
        gll16(pa0 + kk, a_); gll16(pa1 + kk, a_ + 4096);
        gll16(pb0 + kk, b_); gll16(pb1 + kk, b_ + 4096);
    };

    STG(0, 0);
    asm volatile("s_waitcnt vmcnt(0)" ::: "memory");
    __syncthreads();
    f32x4 acc[4][4] = {};
    int cur = 0;
    for (int k0 = 0; k0 < K; k0 += 32) {
        if (k0 + 32 < K) STG(cur ^ 1, k0 + 32);
        const u16* Ab = As + cur*4096;
        const u16* Bb = Bs + cur*4096;
        bf16x8 af[4], bfr[4];
        #pragma unroll
        for (int i = 0; i < 4; i++) {
            af[i]  = *(const bf16x8*)&Ab[(wm*32 + i*8 + (lr>>1))*64 + cs*8];
            bfr[i] = *(const bf16x8*)&Bb[(wn*32 + i*8 + (lr>>1))*64 + cs*8];
        }
        #pragma unroll
        for (int i = 0; i < 4; i++)
            #pragma unroll
            for (int j = 0; j < 4; j++)
                acc[i][j] = mfma16(af[i], bfr[j], acc[i][j]);
        asm volatile("s_waitcnt vmcnt(0)" ::: "memory");
        __syncthreads();
        cur ^= 1;
    }
    #pragma unroll
    for (int i = 0; i < 4; i++) {
        #pragma unroll
        for (int j = 0; j < 4; j++) {
            const int rowl = m0 + wm*64 + i*16 + lg*4;
            const int col  = n0 + wn*64 + j*16 + lr;
            const f32x4 v = acc[i][j];
            #pragma unroll
            for (int r = 0; r < 4; r++) {
                if (rowl + r < cnt) {
                    float xv = v[r];
                    if (EPI == 2) { xv = fmaxf(xv, 0.f); xv = xv * xv; }
                    C[(size_t)(base + rowl + r) * N + col] = (__bf16)xv;
                }
            }
        }
    }
}

// ---------------- split-bf16 MFMA flash attention, causal, balanced pairs ----------------
__global__ __launch_bounds__(256) void attn_mfma(const bf16_t* __restrict__ qkh,
                                                 const bf16_t* __restrict__ qkl,
                                                 const bf16_t* __restrict__ vth,
                                                 const bf16_t* __restrict__ vtl,
                                                 bf16_t* __restrict__ aoh,
                                                 bf16_t* __restrict__ aol) {
    __shared__ u16 KsH[64*64];
    __shared__ u16 KsL[64*64];
    __shared__ u16 VtH[64*64];
    __shared__ u16 VtL[64*64];
    __shared__ u16 P_H[4*16*72];
    __shared__ u16 P_L[4*16*72];
    const int tid = threadIdx.x, lane = tid & 63, wv = tid >> 6;
    const int lr = lane & 15, lg = lane >> 4;
    const int L = blockIdx.x + blockIdx.y*16 + blockIdx.z*256;
    const int swz = (L & 7)*64 + (L >> 3);
    const int qa = swz & 15;
    const int h  = (swz >> 4) & 15;
    const int b  = swz >> 8;
    const int qb = 31 - qa;
    u16* plwH = P_H + wv * 16 * 72;
    u16* plwL = P_L + wv * 16 * 72;
    const int wq0A = qa*64 + wv*16;
    const int wq0B = qb*64 + wv*16;

    bf16x8 qAh[2], qAl[2], qBh[2], qBl[2];
    #pragma unroll
    for (int kf = 0; kf < 2; kf++) {
        const size_t qoA = (size_t)(b*TSEQ + wq0A + lr)*QKN + h*64 + kf*32 + lg*8;
        const size_t qoB = (size_t)(b*TSEQ + wq0B + lr)*QKN + h*64 + kf*32 + lg*8;
        qAh[kf] = *(const bf16x8*)(qkh + qoA);
        qAl[kf] = *(const bf16x8*)(qkl + qoA);
        qBh[kf] = *(const bf16x8*)(qkh + qoB);
        qBl[kf] = *(const bf16x8*)(qkl + qoB);
    }

    f32x4 ofA[4] = {}, ofB[4] = {};
    float mA = -1e30f, lA = 0.f, mB = -1e30f, lB = 0.f;

    const int skv = tid >> 3;
    const int pst = tid & 7;
    const int chs = pst ^ (skv & 7);
    const int bh = b*16 + h;
    const bf16_t* kh = qkh + 1024;
    const bf16_t* kl = qkl + 1024;
    const size_t vrow0 = (size_t)(bh*64 + skv)      * TSEQ;
    const size_t vrow1 = (size_t)(bh*64 + skv + 32) * TSEQ;

    auto step = [&](f32x4 (&of)[4], float& mrun, float& lrun,
                    const bf16x8 (&qfh)[2], const bf16x8 (&qfl)[2],
                    const int wq0, const bool diag, const int kvb) {
        f32x4 sf[4] = {};
        #pragma unroll
        for (int kf = 0; kf < 2; kf++)
            #pragma unroll
            for (int f = 0; f < 4; f++) {
                const int idx = (f*16 + lr)*64 + ((kf*32 + lg*8) ^ ((lr & 7) << 3));
                const bf16x8 ah = *(const bf16x8*)&KsH[idx];
                const bf16x8 al = *(const bf16x8*)&KsL[idx];
                sf[f] = mfma16(ah, qfh[kf], sf[f]);
                sf[f] = mfma16(ah, qfl[kf], sf[f]);
                sf[f] = mfma16(al, qfh[kf], sf[f]);
            }
        if (diag) {
            #pragma unroll
            for (int f = 0; f < 4; f++)
                #pragma unroll
                for (int r = 0; r < 4; r++)
                    if (kvb + f*16 + lg*4 + r > wq0 + lr) sf[f][r] = -1e30f;
        }
        float tm = -1e30f;
        #pragma unroll
        for (int f = 0; f < 4; f++)
            tm = fmaxf(tm, fmaxf(fmaxf(sf[f][0], sf[f][1]), fmaxf(sf[f][2], sf[f][3])));
        tm = fmaxf(tm, __shfl_xor(tm, 16));
        tm = fmaxf(tm, __shfl_xor(tm, 32));
        const float mnew = fmaxf(mrun, tm);
        const float fac = __expf(mrun - mnew);
        mrun = mnew;
        float ps = 0.f;
        #pragma unroll
        for (int f = 0; f < 4; f++) {
            float p[4];
            #pragma unroll
            for (int r = 0; r < 4; r++) { p[r] = __expf(sf[f][r] - mnew); ps += p[r]; }
            u16 hb4[4], lb4[4];
            #pragma unroll
            for (int r = 0; r < 4; r++) {
                const __bf16 hbv = (__bf16)p[r];
                hb4[r] = f2bf(p[r]);
                lb4[r] = f2bf(p[r] - (float)hbv);
            }
            u32* pwh = (u32*)&plwH[lr*72 + f*16 + lg*4];
            u32* pwl = (u32*)&plwL[lr*72 + f*16 + lg*4];
            pwh[0] = (u32)hb4[0] | ((u32)hb4[1] << 16);
            pwh[1] = (u32)hb4[2] | ((u32)hb4[3] << 16);
            pwl[0] = (u32)lb4[0] | ((u32)lb4[1] << 16);
            pwl[1] = (u32)lb4[2] | ((u32)lb4[3] << 16);
        }
        ps += __shfl_xor(ps, 16);
        ps += __shfl_xor(ps, 32);
        lrun = lrun*fac + ps;
        #pragma unroll
        for (int f2 = 0; f2 < 4; f2++)
            #pragma unroll
            for (int r = 0; r < 4; r++) of[f2][r] *= fac;
        #pragma unroll
        for (int hf = 0; hf < 2; hf++) {
            const bf16x8 pbh = *(const bf16x8*)&plwH[lr*72 + hf*32 + lg*8];
            const bf16x8 pbl = *(const bf16x8*)&plwL[lr*72 + hf*32 + lg*8];
            #pragma unroll
            for (int f2 = 0; f2 < 4; f2++) {
                const int vidx = (f2*16 + lr)*64 + (((hf*4 + lg) ^ (lr & 7)) << 3);
                const bf16x8 vah = *(const bf16x8*)&VtH[vidx];
                const bf16x8 val = *(const bf16x8*)&VtL[vidx];
                of[f2] = mfma16(vah, pbh, of[f2]);
                of[f2] = mfma16(vah, pbl, of[f2]);
                of[f2] = mfma16(val, pbh, of[f2]);
            }
        }
    };

    for (int kt = 0; kt <= qb; kt++) {
        __syncthreads();
        const size_t krow = (size_t)(b*TSEQ + kt*64 + skv)*QKN + h*64;
        gll16(kh + krow + chs*8,                     (char*)KsH + tid*16);
        gll16(kh + krow + (size_t)32*QKN + chs*8,    (char*)KsH + 4096 + tid*16);
        gll16(kl + krow + chs*8,                     (char*)KsL + tid*16);
        gll16(kl + krow + (size_t)32*QKN + chs*8,    (char*)KsL + 4096 + tid*16);
        gll16(vth + vrow0 + kt*64 + chs*8,           (char*)VtH + tid*16);
        gll16(vth + vrow1 + kt*64 + chs*8,           (char*)VtH + 4096 + tid*16);
        gll16(vtl + vrow0 + kt*64 + chs*8,           (char*)VtL + tid*16);
        gll16(vtl + vrow1 + kt*64 + chs*8,           (char*)VtL + 4096 + tid*16);
        __syncthreads();
        if (kt <= qa) step(ofA, mA, lA, qAh, qAl, wq0A, kt == qa, kt*64);
        step(ofB, mB, lB, qBh, qBl, wq0B, kt == qb, kt*64);
    }

    const float invA = 1.f / lA, invB = 1.f / lB;
    #pragma unroll
    for (int f2 = 0; f2 < 4; f2++) {
        u16 hb4[4], lb4[4];
        #pragma unroll
        for (int r = 0; r < 4; r++) {
            const float f = ofA[f2][r] * invA;
            const __bf16 hbv = (__bf16)f;
            hb4[r] = f2bf(f);
            lb4[r] = f2bf(f - (float)hbv);
        }
        u32* pwh = (u32*)&plwH[lr*72 + f2*16 + lg*4];
        u32* pwl = (u32*)&plwL[lr*72 + f2*16 + lg*4];
        pwh[0] = (u32)hb4[0] | ((u32)hb4[1] << 16);
        pwh[1] = (u32)hb4[2] | ((u32)hb4[3] << 16);
        pwl[0] = (u32)lb4[0] | ((u32)lb4[1] << 16);
        pwl[1] = (u32)lb4[2] | ((u32)lb4[3] << 16);
    }
    asm volatile("s_waitcnt lgkmcnt(0)" ::: "memory");
    __builtin_amdgcn_sched_barrier(0);
    #pragma unroll
    for (int pass = 0; pass < 2; pass++) {
        const int qlr = pass*8 + (lane >> 3);
        const int ch = (lane & 7) * 8;
        const bf16x8 oh = *(const bf16x8*)&plwH[qlr*72 + ch];
        const bf16x8 ol = *(const bf16x8*)&plwL[qlr*72 + ch];
        const size_t go = (size_t)(b*TSEQ + wq0A + qlr) * DEMB + h*64 + ch;
        *(bf16x8*)(aoh + go) = oh;
        *(bf16x8*)(aol + go) = ol;
    }
    asm volatile("s_waitcnt lgkmcnt(0)" ::: "memory");
    __builtin_amdgcn_sched_barrier(0);
    #pragma unroll
    for (int f2 = 0; f2 < 4; f2++) {
        u16 hb4[4], lb4[4];
        #pragma unroll
        for (int r = 0; r < 4; r++) {
            const float f = ofB[f2][r] * invB;
            const __bf16 hbv = (__bf16)f;
            hb4[r] = f2bf(f);
            lb4[r] = f2bf(f - (float)hbv);
        }
        u32* pwh = (u32*)&plwH[lr*72 + f2*16 + lg*4];
        u32* pwl = (u32*)&plwL[lr*72 + f2*16 + lg*4];
        pwh[0] = (u32)hb4[0] | ((u32)hb4[1] << 16);
        pwh[1] = (u32)hb4[2] | ((u32)hb4[3] << 16);
        pwl[0] = (u32)lb4[0] | ((u32)lb4[1] << 16);
        pwl[1] = (u32)lb4[2] | ((u32)lb4[3] << 16);
    }
    asm volatile("s_waitcnt lgkmcnt(0)" ::: "memory");
    __builtin_amdgcn_sched_barrier(0);
    #pragma unroll
    for (int pass = 0; pass < 2; pass++) {
        const int qlr = pass*8 + (lane >> 3);
        const int ch = (lane & 7) * 8;
        const bf16x8 oh = *(const bf16x8*)&plwH[qlr*72 + ch];
        const bf16x8 ol = *(const bf16x8*)&plwL[qlr*72 + ch];
        const size_t go = (size_t)(b*TSEQ + wq0B + qlr) * DEMB + h*64 + ch;
        *(bf16x8*)(aoh + go) = oh;
        *(bf16x8*)(aol + go) = ol;
    }
}

// ---------------- MoE routing (fp32, rmsnorm folded in; also writes h bf16) ----------
__global__ void zero8(int* c) { if (threadIdx.x < NEXP) c[threadIdx.x] = 0; }

__global__ __launch_bounds__(256) void router_k(const float* __restrict__ xout,
                                                const float* __restrict__ rw,
                                                bf16_t* __restrict__ h,
                                                int* __restrict__ idx,
                                                float* __restrict__ wts,
                                                int* __restrict__ pos,
                                                int* __restrict__ counts) {
    const int tok = blockIdx.x * 4 + (threadIdx.x >> 6);
    const int lane = threadIdx.x & 63;
    const float* xr = xout + (size_t)tok * DEMB;
    float xv16[16];
    float ss = 0.f;
    float acc[NEXP];
    #pragma unroll
    for (int e = 0; e < NEXP; e++) acc[e] = 0.f;
    #pragma unroll
    for (int i = 0; i < 16; i++) {
        const int kk = lane + i*64;
        const float xv = xr[kk];
        xv16[i] = xv;
        ss += xv * xv;
        #pragma unroll
        for (int e = 0; e < NEXP; e++) acc[e] += xv * rw[kk*NEXP + e];
    }
    #pragma unroll
    for (int off = 32; off; off >>= 1) ss += __shfl_xor(ss, off);
    #pragma unroll
    for (int e = 0; e < NEXP; e++) {
        #pragma unroll
        for (int off = 32; off; off >>= 1) acc[e] += __shfl_xor(acc[e], off);
    }
    const float r = rsqrtf(ss * (1.0f/DEMB) + 1e-5f);
    #pragma unroll
    for (int i = 0; i < 16; i++)
        h[(size_t)tok*DEMB + lane + i*64] = (__bf16)(xv16[i] * r);
    if (lane == 0) {
        float v[NEXP];
        #pragma unroll
        for (int e = 0; e < NEXP; e++) v[e] = acc[e] * r;
        int b0 = 0; float v0 = v[0];
        #pragma unroll
        for (int e = 1; e < NEXP; e++) if (v[e] > v0) { v0 = v[e]; b0 = e; }
        int b1 = -1; float v1 = -1e30f;
        #pragma unroll
        for (int e = 0; e < NEXP; e++) if (e != b0 && v[e] > v1) { v1 = v[e]; b1 = e; }
        const float w0 = 1.f / (1.f + __expf(v1 - v0));
        idx[tok*2+0] = b0; idx[tok*2+1] = b1;
        wts[tok*2+0] = w0; wts[tok*2+1] = 1.f - w0;
        pos[tok*2+0] = atomicAdd(&counts[b0], 1);
        pos[tok*2+1] = atomicAdd(&counts[b1], 1);
    }
}

__global__ void offsets_k(const int* __restrict__ counts, int* __restrict__ offs) {
    if (threadIdx.x == 0) {
        int s = 0;
        for (int e = 0; e < NEXP; e++) { offs[e] = s; s += counts[e]; }
    }
}

__global__ __launch_bounds__(256) void buildmap_k(const int* __restrict__ idx,
                                                  const int* __restrict__ pos,
                                                  const int* __restrict__ offs,
                                                  int* __restrict__ rowmap,
                                                  int* __restrict__ rowpos) {
    const int n = blockIdx.x * 256 + threadIdx.x;
    #pragma unroll
    for (int s = 0; s < 2; s++) {
        const int e = idx[n*2+s];
        const int r = offs[e] + pos[n*2+s];
        rowmap[r] = n;
        rowpos[n*2+s] = r;
    }
}

__global__ __launch_bounds__(256) void combine_k(const bf16_t* __restrict__ oe,
                                                 const int* __restrict__ rowpos,
                                                 const float* __restrict__ wts,
                                                 float* __restrict__ out) {
    const int n = blockIdx.x;
    const int r0 = rowpos[n*2+0], r1 = rowpos[n*2+1];
    const float w0 = wts[n*2+0], w1 = wts[n*2+1];
    const int c = threadIdx.x * 4;
    const bf16x4 a  = *(const bf16x4*)(oe + (size_t)r0*DEMB + c);
    const bf16x4 b4 = *(const bf16x4*)(oe + (size_t)r1*DEMB + c);
    float4* op = (float4*)(out + (size_t)n*DEMB + c);
    float4 o = *op;
    o.x += w0*(float)a[0] + w1*(float)b4[0];
    o.y += w0*(float)a[1] + w1*(float)b4[1];
    o.z += w0*(float)a[2] + w1*(float)b4[2];
    o.w += w0*(float)a[3] + w1*(float)b4[3];
    *op = o;
}

extern "C" void kernel_launch(void* const* d_in, const int* in_sizes, int n_in,
                              void* d_out, int out_size, void* d_ws, size_t ws_size,
                              hipStream_t stream) {
    (void)in_sizes; (void)n_in; (void)out_size; (void)ws_size;
    const float* x   = (const float*)d_in[0];
    const float* wq  = (const float*)d_in[1];
    const float* wk  = (const float*)d_in[2];
    const float* wv  = (const float*)d_in[3];
    const float* wo  = (const float*)d_in[4];
    const float* rw  = (const float*)d_in[5];
    const float* fc1 = (const float*)d_in[6];
    const float* fc2 = (const float*)d_in[7];
    float* out = (float*)d_out;
    char* ws = (char*)d_ws;
    const size_t MB = 1024*1024;

    bf16_t* wqkv_h = (bf16_t*)(ws);
    bf16_t* wqkv_l = (bf16_t*)(ws + 6*MB);
    bf16_t* wo_h   = (bf16_t*)(ws + 12*MB);
    bf16_t* wo_l   = (bf16_t*)(ws + 14*MB);
    bf16_t* qk_h   = (bf16_t*)(ws + 16*MB);
    bf16_t* qk_l   = (bf16_t*)(ws + 32*MB);
    bf16_t* vt_h   = (bf16_t*)(ws + 48*MB);
    bf16_t* vt_l   = (bf16_t*)(ws + 56*MB);
    bf16_t* fc1_t  = (bf16_t*)(ws + 16*MB);
    bf16_t* fc2_t  = (bf16_t*)(ws + 48*MB);
    bf16_t* h_hi   = (bf16_t*)(ws + 64*MB);
    bf16_t* h_lo   = (bf16_t*)(ws + 72*MB);
    bf16_t* ao_h   = (bf16_t*)(ws + 64*MB);
    bf16_t* ao_l   = (bf16_t*)(ws + 72*MB);
    bf16_t* h      = (bf16_t*)(ws + 80*MB);
    bf16_t* h1     = (bf16_t*)(ws + 88*MB);
    bf16_t* oe     = (bf16_t*)(ws);
    char* meta = ws + 120*MB;
    int*   idx    = (int*)(meta);
    int*   pos    = (int*)(meta + 64*1024);
    int*   rowmap = (int*)(meta + 128*1024);
    int*   rowpos = (int*)(meta + 192*1024);
    float* wts    = (float*)(meta + 256*1024);
    int*   counts = (int*)(meta + 320*1024);
    int*   offs   = (int*)(meta + 320*1024 + 256);

    const dim3 blk(256);

    // ---- attention path ----
    transp_split_k<<<dim3(32,32), blk, 0, stream>>>(wq, wqkv_h,               wqkv_l,               1024, 1024);
    transp_split_k<<<dim3(32,32), blk, 0, stream>>>(wk, wqkv_h + 1024*1024,   wqkv_l + 1024*1024,   1024, 1024);
    transp_split_k<<<dim3(32,32), blk, 0, stream>>>(wv, wqkv_h + 2*1024*1024, wqkv_l + 2*1024*1024, 1024, 1024);
    transp_split_k<<<dim3(32,32), blk, 0, stream>>>(wo, wo_h,                 wo_l,                 1024, 1024);
    rmsnorm_split_k<<<NTOK, blk, 0, stream>>>(x, h_hi, h_lo);
    gemm_qkv256<<<dim3(12, 16), dim3(512), 0, stream>>>(
        h_hi, h_lo, wqkv_h, wqkv_l, qk_h, qk_l, vt_h, vt_l);
    attn_mfma<<<dim3(16, 16, 2), blk, 0, stream>>>(qk_h, qk_l, vt_h, vt_l, ao_h, ao_l);
    gemm_split<1><<<dim3(DEMB/128, NTOK/128), blk, 0, stream>>>(
        ao_h, ao_l, wo_h, wo_l, x, out, DEMB, 1024);

    // ---- MoE path (fp32 router + rmsnorm fold, bf16 experts) ----
    transp_k<<<dim3(64,32,8), blk, 0, stream>>>(fc1, fc1_t, 1024, 2048);
    transp_k<<<dim3(32,64,8), blk, 0, stream>>>(fc2, fc2_t, 2048, 1024);
    zero8<<<1, 64, 0, stream>>>(counts);
    router_k<<<NTOK/4, blk, 0, stream>>>(out, rw, h, idx, wts, pos, counts);
    offsets_k<<<1, 64, 0, stream>>>(counts, offs);
    buildmap_k<<<NTOK/256, blk, 0, stream>>>(idx, pos, offs, rowmap, rowpos);
    gemm_moe<2,1><<<dim3(EDIM/128, 32, NEXP), blk, 0, stream>>>(
        h, fc1_t, h1, rowmap, counts, offs, EDIM, 1024);
    gemm_moe<3,0><<<dim3(DEMB/128, 32, NEXP), blk, 0, stream>>>(
        h1, fc2_t, oe, rowmap, counts, offs, DEMB, EDIM);
    combine_k<<<NTOK, blk, 0, stream>>>(oe, rowpos, wts, out);
}

// Round 11
// 430.062 us; speedup vs baseline: 1.2831x; 1.1810x over previous
//
#include <hip/hip_runtime.h>
#include <math.h>

#define NTOK 4096
#define DEMB 1024
#define TSEQ 2048
#define QKVS 3072
#define QKN  2048
#define EDIM 2048
#define NEXP 8

typedef unsigned short u16;
typedef unsigned int u32;
typedef __bf16 bf16_t;
typedef __bf16 bf16x8 __attribute__((ext_vector_type(8)));
typedef __bf16 bf16x4 __attribute__((ext_vector_type(4)));
typedef float f32x4 __attribute__((ext_vector_type(4)));

__device__ __forceinline__ f32x4 mfma16(bf16x8 a, bf16x8 b, f32x4 c) {
    return __builtin_amdgcn_mfma_f32_16x16x32_bf16(a, b, c, 0, 0, 0);
}
__device__ __forceinline__ void gll16(const void* g, void* l) {
    __builtin_amdgcn_global_load_lds((const __attribute__((address_space(1))) u32*)g,
                                     (__attribute__((address_space(3))) u32*)l, 16, 0, 0);
}
__device__ __forceinline__ u16 f2bf(float x) {
    union { __bf16 h; u16 u; } c; c.h = (__bf16)x; return c.u;
}

// ---------------- rmsnorm fp32 -> split bf16 (hi, lo) ----------------
__global__ __launch_bounds__(256) void rmsnorm_split_k(const float* __restrict__ x,
                                                       bf16_t* __restrict__ hi,
                                                       bf16_t* __restrict__ lo) {
    const int row = blockIdx.x;
    const float4 v = ((const float4*)(x + (size_t)row * DEMB))[threadIdx.x];
    float ss = v.x*v.x + v.y*v.y + v.z*v.z + v.w*v.w;
    #pragma unroll
    for (int off = 32; off; off >>= 1) ss += __shfl_xor(ss, off);
    __shared__ float wsum[4];
    if ((threadIdx.x & 63) == 0) wsum[threadIdx.x >> 6] = ss;
    __syncthreads();
    const float r = rsqrtf((wsum[0]+wsum[1]+wsum[2]+wsum[3]) * (1.0f/DEMB) + 1e-5f);
    const float f[4] = {v.x*r, v.y*r, v.z*r, v.w*r};
    bf16x4 hv, lv;
    #pragma unroll
    for (int j = 0; j < 4; j++) {
        const __bf16 hb = (__bf16)f[j];
        hv[j] = hb;
        lv[j] = (__bf16)(f[j] - (float)hb);
    }
    ((bf16x4*)(hi + (size_t)row*DEMB))[threadIdx.x] = hv;
    ((bf16x4*)(lo + (size_t)row*DEMB))[threadIdx.x] = lv;
}

// ---------------- weight transpose fp32 [K][M] -> split bf16 [M][K] ----------------
__global__ __launch_bounds__(256) void transp_split_k(const float* __restrict__ w,
                                                      bf16_t* __restrict__ wth,
                                                      bf16_t* __restrict__ wtl,
                                                      int K, int M) {
    __shared__ float t[32][33];
    const int m0 = blockIdx.x*32, k0 = blockIdx.y*32;
    const int tx = threadIdx.x & 31, ty = threadIdx.x >> 5;
    #pragma unroll
    for (int i = 0; i < 32; i += 8) t[ty+i][tx] = w[(size_t)(k0+ty+i)*M + m0+tx];
    __syncthreads();
    #pragma unroll
    for (int i = 0; i < 32; i += 8) {
        const float f = t[tx][ty+i];
        const __bf16 hb = (__bf16)f;
        wth[(size_t)(m0+ty+i)*K + k0+tx] = hb;
        wtl[(size_t)(m0+ty+i)*K + k0+tx] = (__bf16)(f - (float)hb);
    }
}

// ---------------- weight transpose fp32 [K][M] -> plain bf16 [M][K] (per expert) ------
__global__ __launch_bounds__(256) void transp_k(const float* __restrict__ w,
                                                bf16_t* __restrict__ wt,
                                                int K, int M) {
    __shared__ float t[32][33];
    const size_t eo = (size_t)blockIdx.z * K * M;
    w += eo; wt += eo;
    const int m0 = blockIdx.x*32, k0 = blockIdx.y*32;
    const int tx = threadIdx.x & 31, ty = threadIdx.x >> 5;
    #pragma unroll
    for (int i = 0; i < 32; i += 8) t[ty+i][tx] = w[(size_t)(k0+ty+i)*M + m0+tx];
    __syncthreads();
    #pragma unroll
    for (int i = 0; i < 32; i += 8) wt[(size_t)(m0+ty+i)*K + k0+tx] = (__bf16)t[tx][ty+i];
}

// ---------------- QKV split-bf16 GEMM, 256x256 tile, 8 waves, 2-phase/K-tile ----------
__global__ __launch_bounds__(512) void gemm_qkv256(const bf16_t* __restrict__ Ah,
                                                   const bf16_t* __restrict__ Al,
                                                   const bf16_t* __restrict__ Bh,
                                                   const bf16_t* __restrict__ Bl,
                                                   bf16_t* __restrict__ qkh,
                                                   bf16_t* __restrict__ qkl,
                                                   bf16_t* __restrict__ vth,
                                                   bf16_t* __restrict__ vtl) {
    __shared__ u16 As[2*16384];
    __shared__ u16 Bs[2*16384];
    const int tid = threadIdx.x;
    const int lane = tid & 63, w = tid >> 6;
    const int lr = lane & 15, lg = lane >> 4;
    const int wm = w >> 2, wn = w & 3;
    int flat = blockIdx.y * 12 + blockIdx.x;
    flat = (flat & 7) * 24 + (flat >> 3);
    const int m0 = (flat / 12) * 256, n0 = (flat % 12) * 256;

    const int srow = tid >> 3;                 // 0..63
    const int sd   = (tid & 7) ^ (srow & 7);
    const int kofs = (sd & 3) * 8;
    const bf16_t* Asrc = (sd < 4) ? Ah : Al;
    const bf16_t* Bsrc = (sd < 4) ? Bh : Bl;
    const bf16_t* pA0 = Asrc + (size_t)(m0 + srow      ) * 1024 + kofs;
    const bf16_t* pA1 = Asrc + (size_t)(m0 + srow +  64) * 1024 + kofs;
    const bf16_t* pA2 = Asrc + (size_t)(m0 + srow + 128) * 1024 + kofs;
    const bf16_t* pA3 = Asrc + (size_t)(m0 + srow + 192) * 1024 + kofs;
    const bf16_t* pB0 = Bsrc + (size_t)(n0 + srow      ) * 1024 + kofs;
    const bf16_t* pB1 = Bsrc + (size_t)(n0 + srow +  64) * 1024 + kofs;
    const bf16_t* pB2 = Bsrc + (size_t)(n0 + srow + 128) * 1024 + kofs;
    const bf16_t* pB3 = Bsrc + (size_t)(n0 + srow + 192) * 1024 + kofs;
    const int ca = (lg ^ (lr & 7)) * 8;

#define STG_Q(u_, kn_, nb_) do { \
    gll16(pA##u_ + (kn_), (char*)As + (nb_)*32768 + (u_)*8192 + tid*16); \
    gll16(pB##u_ + (kn_), (char*)Bs + (nb_)*32768 + (u_)*8192 + tid*16); } while (0)

    STG_Q(0, 0, 0); STG_Q(1, 0, 0); STG_Q(2, 0, 0); STG_Q(3, 0, 0);
    asm volatile("s_waitcnt vmcnt(0)" ::: "memory");
    __builtin_amdgcn_sched_barrier(0);
    __syncthreads();

    f32x4 acc[8][4] = {};
    int cur = 0;
    for (int t = 0; t < 32; t++) {
        const u16* Ab = As + cur*16384;
        const u16* Bb = Bs + cur*16384;
        const int nb = cur ^ 1;
        const int kn = (t + 1) * 32;
        const bool more = (t < 31);

        bf16x8 bh[4], bl[4];
        #pragma unroll
        for (int j = 0; j < 4; j++) {
            const int bo = (wn*64 + j*16 + lr)*64 + ca;
            bh[j] = *(const bf16x8*)&Bb[bo];
            bl[j] = *(const bf16x8*)&Bb[bo ^ 32];
        }
        {
            bf16x8 ah[4], al[4];
            #pragma unroll
            for (int i = 0; i < 4; i++) {
                const int ao = (wm*128 + i*16 + lr)*64 + ca;
                ah[i] = *(const bf16x8*)&Ab[ao];
                al[i] = *(const bf16x8*)&Ab[ao ^ 32];
            }
            if (more) { STG_Q(0, kn, nb); STG_Q(1, kn, nb); }
            __builtin_amdgcn_s_barrier();
            asm volatile("s_waitcnt lgkmcnt(0)" ::: "memory");
            __builtin_amdgcn_sched_barrier(0);
            __builtin_amdgcn_s_setprio(1);
            #pragma unroll
            for (int i = 0; i < 4; i++)
                #pragma unroll
                for (int j = 0; j < 4; j++) {
                    acc[i][j] = mfma16(ah[i], bh[j], acc[i][j]);
                    acc[i][j] = mfma16(ah[i], bl[j], acc[i][j]);
                    acc[i][j] = mfma16(al[i], bh[j], acc[i][j]);
                }
            __builtin_amdgcn_s_setprio(0);
            __builtin_amdgcn_s_barrier();
        }
        {
            bf16x8 ah[4], al[4];
            #pragma unroll
            for (int i = 0; i < 4; i++) {
                const int ao = (wm*128 + 64 + i*16 + lr)*64 + ca;
                ah[i] = *(const bf16x8*)&Ab[ao];
                al[i] = *(const bf16x8*)&Ab[ao ^ 32];
            }
            if (more) { STG_Q(2, kn, nb); STG_Q(3, kn, nb); }
            __builtin_amdgcn_s_barrier();
            asm volatile("s_waitcnt lgkmcnt(0)" ::: "memory");
            __builtin_amdgcn_sched_barrier(0);
            __builtin_amdgcn_s_setprio(1);
            #pragma unroll
            for (int i = 0; i < 4; i++)
                #pragma unroll
                for (int j = 0; j < 4; j++) {
                    acc[4+i][j] = mfma16(ah[i], bh[j], acc[4+i][j]);
                    acc[4+i][j] = mfma16(ah[i], bl[j], acc[4+i][j]);
                    acc[4+i][j] = mfma16(al[i], bh[j], acc[4+i][j]);
                }
            __builtin_amdgcn_s_setprio(0);
            asm volatile("s_waitcnt vmcnt(0)" ::: "memory");
            __builtin_amdgcn_sched_barrier(0);
            __builtin_amdgcn_s_barrier();
        }
        cur ^= 1;
    }
#undef STG_Q
    #pragma unroll
    for (int i = 0; i < 8; i++) {
        #pragma unroll
        for (int j = 0; j < 4; j++) {
            const int row = m0 + wm*128 + i*16 + lg*4;
            const int col = n0 + wn*64 + j*16 + lr;
            const f32x4 v = acc[i][j];
            if (col < QKN) {
                const float sc = (col < DEMB) ? 0.125f : 1.0f;
                #pragma unroll
                for (int r = 0; r < 4; r++) {
                    const size_t o = (size_t)(row + r) * QKN + col;
                    const float f = v[r] * sc;
                    const __bf16 hb = (__bf16)f;
                    qkh[o] = hb;
                    qkl[o] = (__bf16)(f - (float)hb);
                }
            } else {
                const int d = col - QKN;
                const int hh = d >> 6, dd = d & 63;
                const int bb = row >> 11, tt = row & 2047;
                const size_t base = ((size_t)(bb*16 + hh)*64 + dd) * TSEQ + tt;
                #pragma unroll
                for (int r = 0; r < 4; r++) {
                    const float f = v[r];
                    const __bf16 hb = (__bf16)f;
                    vth[base + r] = hb;
                    vtl[base + r] = (__bf16)(f - (float)hb);
                }
            }
        }
    }
}

// ---------------- 128² split-bf16 GEMM (WO): 2-phase dbuf, packed HI|LO rows ----------
template<int EPI>
__global__ __launch_bounds__(256) void gemm_split(const bf16_t* __restrict__ Ah,
                                                  const bf16_t* __restrict__ Al,
                                                  const bf16_t* __restrict__ Bh,
                                                  const bf16_t* __restrict__ Bl,
                                                  const float* __restrict__ res,
                                                  float* __restrict__ C,
                                                  int N, int K) {
    __shared__ u16 As[16384];
    __shared__ u16 Bs[16384];
    const int tid = threadIdx.x;
    const int lane = tid & 63, w = tid >> 6;
    const int lr = lane & 15, lg = lane >> 4;
    const int wm = w >> 1, wn = w & 1;
    const int nbx = gridDim.x;
    const int nwg = gridDim.x * gridDim.y;
    int flat = blockIdx.y * nbx + blockIdx.x;
    flat = (flat & 7) * (nwg >> 3) + (flat >> 3);
    const int m0 = (flat / nbx) * 128, n0 = (flat % nbx) * 128;

    const int srow = tid >> 3;
    const int sd   = (tid & 7) ^ (srow & 7);
    const int kofs = (sd & 3) * 8;
    const bf16_t* Asrc = (sd < 4) ? Ah : Al;
    const bf16_t* Bsrc = (sd < 4) ? Bh : Bl;
    const bf16_t* pa0 = Asrc + (size_t)(m0 + srow     ) * K + kofs;
    const bf16_t* pa1 = Asrc + (size_t)(m0 + srow + 32) * K + kofs;
    const bf16_t* pa2 = Asrc + (size_t)(m0 + srow + 64) * K + kofs;
    const bf16_t* pa3 = Asrc + (size_t)(m0 + srow + 96) * K + kofs;
    const bf16_t* pb0 = Bsrc + (size_t)(n0 + srow     ) * K + kofs;
    const bf16_t* pb1 = Bsrc + (size_t)(n0 + srow + 32) * K + kofs;
    const bf16_t* pb2 = Bsrc + (size_t)(n0 + srow + 64) * K + kofs;
    const bf16_t* pb3 = Bsrc + (size_t)(n0 + srow + 96) * K + kofs;
    char* dA = (char*)As + tid*16;
    char* dB = (char*)Bs + tid*16;
    const int ca = (lg ^ (lr & 7)) * 8;

    auto STG = [&](int bsel, int kk) {
        char* a_ = dA + bsel*16384;
        char* b_ = dB + bsel*16384;
        gll16(pa0 + kk, a_);          gll16(pa1 + kk, a_ + 4096);
        gll16(pa2 + kk, a_ + 8192);   gll16(pa3 + kk, a_ + 12288);
        gll16(pb0 + kk, b_);          gll16(pb1 + kk, b_ + 4096);
        gll16(pb2 + kk, b_ + 8192);   gll16(pb3 + kk, b_ + 12288);
    };

    STG(0, 0);
    asm volatile("s_waitcnt vmcnt(0)" ::: "memory");
    __syncthreads();
    f32x4 acc[4][4] = {};
    int cur = 0;
    for (int k0 = 0; k0 < K; k0 += 32) {
        if (k0 + 32 < K) STG(cur ^ 1, k0 + 32);
        const u16* Ab = As + cur*8192;
        const u16* Bb = Bs + cur*8192;
        bf16x8 ah[4], al[4], bh[4], bl[4];
        #pragma unroll
        for (int i = 0; i < 4; i++) {
            const int ao = (wm*64 + i*16 + lr)*64 + ca;
            const int bo = (wn*64 + i*16 + lr)*64 + ca;
            ah[i] = *(const bf16x8*)&Ab[ao];
            al[i] = *(const bf16x8*)&Ab[ao ^ 32];
            bh[i] = *(const bf16x8*)&Bb[bo];
            bl[i] = *(const bf16x8*)&Bb[bo ^ 32];
        }
        #pragma unroll
        for (int i = 0; i < 4; i++)
            #pragma unroll
            for (int j = 0; j < 4; j++) {
                acc[i][j] = mfma16(ah[i], bh[j], acc[i][j]);
                acc[i][j] = mfma16(ah[i], bl[j], acc[i][j]);
                acc[i][j] = mfma16(al[i], bh[j], acc[i][j]);
            }
        asm volatile("s_waitcnt vmcnt(0)" ::: "memory");
        __syncthreads();
        cur ^= 1;
    }
    #pragma unroll
    for (int i = 0; i < 4; i++) {
        #pragma unroll
        for (int j = 0; j < 4; j++) {
            const int row = m0 + wm*64 + i*16 + lg*4;
            const int col = n0 + wn*64 + j*16 + lr;
            const f32x4 v = acc[i][j];
            #pragma unroll
            for (int r = 0; r < 4; r++) {
                const size_t o = (size_t)(row + r) * N + col;
                C[o] = res[o] + v[r];
            }
        }
    }
}

// ---------------- grouped per-expert bf16 GEMM (EPI 2: relu^2; EPI 3: plain) ----------
template<int EPI, int GATHER>
__global__ __launch_bounds__(256) void gemm_moe(const bf16_t* __restrict__ A,
                                                const bf16_t* __restrict__ Ball,
                                                bf16_t* __restrict__ C,
                                                const int* __restrict__ rowmap,
                                                const int* __restrict__ counts,
                                                const int* __restrict__ offs,
                                                int N, int K) {
    const int e = blockIdx.z;
    const int cnt = counts[e];
    if ((int)blockIdx.y * 128 >= cnt) return;
    const int base = offs[e];
    const bf16_t* Bt = Ball + (size_t)e * N * K;
    __shared__ u16 As[8192];
    __shared__ u16 Bs[8192];
    const int tid = threadIdx.x;
    const int lane = tid & 63, w = tid >> 6;
    const int lr = lane & 15, lg = lane >> 4;
    const int wm = w >> 1, wn = w & 1;
    const int m0 = blockIdx.y * 128, n0 = blockIdx.x * 128;

    const int srp = tid >> 3;
    const int sd  = (tid & 7) ^ (srp & 7);
    const int smrow = 2*srp + (sd >> 2);
    const int kofs  = (sd & 3) * 8;
    const int l0 = min(m0 + smrow, cnt - 1), l1 = min(m0 + 64 + smrow, cnt - 1);
    const size_t r0 = GATHER ? (size_t)rowmap[base + l0] : (size_t)(base + l0);
    const size_t r1 = GATHER ? (size_t)rowmap[base + l1] : (size_t)(base + l1);
    const bf16_t* pa0 = A + r0 * K + kofs;
    const bf16_t* pa1 = A + r1 * K + kofs;
    const bf16_t* pb0 = Bt + (size_t)(n0 + smrow)      * K + kofs;
    const bf16_t* pb1 = Bt + (size_t)(n0 + 64 + smrow) * K + kofs;
    char* dA = (char*)As + tid*16;
    char* dB = (char*)Bs + tid*16;
    const int cs = (((lr & 1) << 2) + lg) ^ ((lr >> 1) & 7);

    auto STG = [&](int bsel, int kk) {
        char* a_ = dA + bsel*8192;
        char* b_ = dB + bsel*8192;
        gll16(pa0 + kk, a_); gll16(pa1 + kk, a_ + 4096);
        gll16(pb0 + kk, b_); gll16(pb1 + kk, b_ + 4096);
    };

    STG(0, 0);
    asm volatile("s_waitcnt vmcnt(0)" ::: "memory");
    __syncthreads();
    f32x4 acc[4][4] = {};
    int cur = 0;
    for (int k0 = 0; k0 < K; k0 += 32) {
        if (k0 + 32 < K) STG(cur ^ 1, k0 + 32);
        const u16* Ab = As + cur*4096;
        const u16* Bb = Bs + cur*4096;
        bf16x8 af[4], bfr[4];
        #pragma unroll
        for (int i = 0; i < 4; i++) {
            af[i]  = *(const bf16x8*)&Ab[(wm*32 + i*8 + (lr>>1))*64 + cs*8];
            bfr[i] = *(const bf16x8*)&Bb[(wn*32 + i*8 + (lr>>1))*64 + cs*8];
        }
        #pragma unroll
        for (int i = 0; i < 4; i++)
            #pragma unroll
            for (int j = 0; j < 4; j++)
                acc[i][j] = mfma16(af[i], bfr[j], acc[i][j]);
        asm volatile("s_waitcnt vmcnt(0)" ::: "memory");
        __syncthreads();
        cur ^= 1;
    }
    #pragma unroll
    for (int i = 0; i < 4; i++) {
        #pragma unroll
        for (int j = 0; j < 4; j++) {
            const int rowl = m0 + wm*64 + i*16 + lg*4;
            const int col  = n0 + wn*64 + j*16 + lr;
            const f32x4 v = acc[i][j];
            #pragma unroll
            for (int r = 0; r < 4; r++) {
                if (rowl + r < cnt) {
                    float xv = v[r];
                    if (EPI == 2) { xv = fmaxf(xv, 0.f); xv = xv * xv; }
                    C[(size_t)(base + rowl + r) * N + col] = (__bf16)xv;
                }
            }
        }
    }
}

// ---------------- split-bf16 MFMA flash attention, causal, balanced pairs ----------------
__global__ __launch_bounds__(256) void attn_mfma(const bf16_t* __restrict__ qkh,
                                                 const bf16_t* __restrict__ qkl,
                                                 const bf16_t* __restrict__ vth,
                                                 const bf16_t* __restrict__ vtl,
                                                 bf16_t* __restrict__ aoh,
                                                 bf16_t* __restrict__ aol) {
    __shared__ u16 KsH[64*64];
    __shared__ u16 KsL[64*64];
    __shared__ u16 VtH[64*64];
    __shared__ u16 VtL[64*64];
    __shared__ u16 P_H[4*16*72];
    __shared__ u16 P_L[4*16*72];
    const int tid = threadIdx.x, lane = tid & 63, wv = tid >> 6;
    const int lr = lane & 15, lg = lane >> 4;
    const int L = blockIdx.x + blockIdx.y*16 + blockIdx.z*256;
    const int swz = (L & 7)*64 + (L >> 3);
    const int qa = swz & 15;
    const int h  = (swz >> 4) & 15;
    const int b  = swz >> 8;
    const int qb = 31 - qa;
    u16* plwH = P_H + wv * 16 * 72;
    u16* plwL = P_L + wv * 16 * 72;
    const int wq0A = qa*64 + wv*16;
    const int wq0B = qb*64 + wv*16;

    bf16x8 qAh[2], qAl[2], qBh[2], qBl[2];
    #pragma unroll
    for (int kf = 0; kf < 2; kf++) {
        const size_t qoA = (size_t)(b*TSEQ + wq0A + lr)*QKN + h*64 + kf*32 + lg*8;
        const size_t qoB = (size_t)(b*TSEQ + wq0B + lr)*QKN + h*64 + kf*32 + lg*8;
        qAh[kf] = *(const bf16x8*)(qkh + qoA);
        qAl[kf] = *(const bf16x8*)(qkl + qoA);
        qBh[kf] = *(const bf16x8*)(qkh + qoB);
        qBl[kf] = *(const bf16x8*)(qkl + qoB);
    }

    f32x4 ofA[4] = {}, ofB[4] = {};
    float mA = -1e30f, lA = 0.f, mB = -1e30f, lB = 0.f;

    const int skv = tid >> 3;
    const int pst = tid & 7;
    const int chs = pst ^ (skv & 7);
    const int bh = b*16 + h;
    const bf16_t* kh = qkh + 1024;
    const bf16_t* kl = qkl + 1024;
    const size_t vrow0 = (size_t)(bh*64 + skv)      * TSEQ;
    const size_t vrow1 = (size_t)(bh*64 + skv + 32) * TSEQ;

    auto step = [&](f32x4 (&of)[4], float& mrun, float& lrun,
                    const bf16x8 (&qfh)[2], const bf16x8 (&qfl)[2],
                    const int wq0, const bool diag, const int kvb) {
        f32x4 sf[4] = {};
        #pragma unroll
        for (int kf = 0; kf < 2; kf++)
            #pragma unroll
            for (int f = 0; f < 4; f++) {
                const int idx = (f*16 + lr)*64 + ((kf*32 + lg*8) ^ ((lr & 7) << 3));
                const bf16x8 ah = *(const bf16x8*)&KsH[idx];
                const bf16x8 al = *(const bf16x8*)&KsL[idx];
                sf[f] = mfma16(ah, qfh[kf], sf[f]);
                sf[f] = mfma16(ah, qfl[kf], sf[f]);
                sf[f] = mfma16(al, qfh[kf], sf[f]);
            }
        if (diag) {
            #pragma unroll
            for (int f = 0; f < 4; f++)
                #pragma unroll
                for (int r = 0; r < 4; r++)
                    if (kvb + f*16 + lg*4 + r > wq0 + lr) sf[f][r] = -1e30f;
        }
        float tm = -1e30f;
        #pragma unroll
        for (int f = 0; f < 4; f++)
            tm = fmaxf(tm, fmaxf(fmaxf(sf[f][0], sf[f][1]), fmaxf(sf[f][2], sf[f][3])));
        tm = fmaxf(tm, __shfl_xor(tm, 16));
        tm = fmaxf(tm, __shfl_xor(tm, 32));
        const float mnew = fmaxf(mrun, tm);
        const float fac = __expf(mrun - mnew);
        mrun = mnew;
        float ps = 0.f;
        #pragma unroll
        for (int f = 0; f < 4; f++) {
            float p[4];
            #pragma unroll
            for (int r = 0; r < 4; r++) { p[r] = __expf(sf[f][r] - mnew); ps += p[r]; }
            u16 hb4[4], lb4[4];
            #pragma unroll
            for (int r = 0; r < 4; r++) {
                const __bf16 hbv = (__bf16)p[r];
                hb4[r] = f2bf(p[r]);
                lb4[r] = f2bf(p[r] - (float)hbv);
            }
            u32* pwh = (u32*)&plwH[lr*72 + f*16 + lg*4];
            u32* pwl = (u32*)&plwL[lr*72 + f*16 + lg*4];
            pwh[0] = (u32)hb4[0] | ((u32)hb4[1] << 16);
            pwh[1] = (u32)hb4[2] | ((u32)hb4[3] << 16);
            pwl[0] = (u32)lb4[0] | ((u32)lb4[1] << 16);
            pwl[1] = (u32)lb4[2] | ((u32)lb4[3] << 16);
        }
        ps += __shfl_xor(ps, 16);
        ps += __shfl_xor(ps, 32);
        lrun = lrun*fac + ps;
        #pragma unroll
        for (int f2 = 0; f2 < 4; f2++)
            #pragma unroll
            for (int r = 0; r < 4; r++) of[f2][r] *= fac;
        #pragma unroll
        for (int hf = 0; hf < 2; hf++) {
            const bf16x8 pbh = *(const bf16x8*)&plwH[lr*72 + hf*32 + lg*8];
            const bf16x8 pbl = *(const bf16x8*)&plwL[lr*72 + hf*32 + lg*8];
            #pragma unroll
            for (int f2 = 0; f2 < 4; f2++) {
                const int vidx = (f2*16 + lr)*64 + (((hf*4 + lg) ^ (lr & 7)) << 3);
                const bf16x8 vah = *(const bf16x8*)&VtH[vidx];
                const bf16x8 val = *(const bf16x8*)&VtL[vidx];
                of[f2] = mfma16(vah, pbh, of[f2]);
                of[f2] = mfma16(vah, pbl, of[f2]);
                of[f2] = mfma16(val, pbh, of[f2]);
            }
        }
    };

    for (int kt = 0; kt <= qb; kt++) {
        __syncthreads();
        const size_t krow = (size_t)(b*TSEQ + kt*64 + skv)*QKN + h*64;
        gll16(kh + krow + chs*8,                     (char*)KsH + tid*16);
        gll16(kh + krow + (size_t)32*QKN + chs*8,    (char*)KsH + 4096 + tid*16);
        gll16(kl + krow + chs*8,                     (char*)KsL + tid*16);
        gll16(kl + krow + (size_t)32*QKN + chs*8,    (char*)KsL + 4096 + tid*16);
        gll16(vth + vrow0 + kt*64 + chs*8,           (char*)VtH + tid*16);
        gll16(vth + vrow1 + kt*64 + chs*8,           (char*)VtH + 4096 + tid*16);
        gll16(vtl + vrow0 + kt*64 + chs*8,           (char*)VtL + tid*16);
        gll16(vtl + vrow1 + kt*64 + chs*8,           (char*)VtL + 4096 + tid*16);
        __syncthreads();
        if (kt <= qa) step(ofA, mA, lA, qAh, qAl, wq0A, kt == qa, kt*64);
        step(ofB, mB, lB, qBh, qBl, wq0B, kt == qb, kt*64);
    }

    const float invA = 1.f / lA, invB = 1.f / lB;
    #pragma unroll
    for (int f2 = 0; f2 < 4; f2++) {
        u16 hb4[4], lb4[4];
        #pragma unroll
        for (int r = 0; r < 4; r++) {
            const float f = ofA[f2][r] * invA;
            const __bf16 hbv = (__bf16)f;
            hb4[r] = f2bf(f);
            lb4[r] = f2bf(f - (float)hbv);
        }
        u32* pwh = (u32*)&plwH[lr*72 + f2*16 + lg*4];
        u32* pwl = (u32*)&plwL[lr*72 + f2*16 + lg*4];
        pwh[0] = (u32)hb4[0] | ((u32)hb4[1] << 16);
        pwh[1] = (u32)hb4[2] | ((u32)hb4[3] << 16);
        pwl[0] = (u32)lb4[0] | ((u32)lb4[1] << 16);
        pwl[1] = (u32)lb4[2] | ((u32)lb4[3] << 16);
    }
    asm volatile("s_waitcnt lgkmcnt(0)" ::: "memory");
    __builtin_amdgcn_sched_barrier(0);
    #pragma unroll
    for (int pass = 0; pass < 2; pass++) {
        const int qlr = pass*8 + (lane >> 3);
        const int ch = (lane & 7) * 8;
        const bf16x8 oh = *(const bf16x8*)&plwH[qlr*72 + ch];
        const bf16x8 ol = *(const bf16x8*)&plwL[qlr*72 + ch];
        const size_t go = (size_t)(b*TSEQ + wq0A + qlr) * DEMB + h*64 + ch;
        *(bf16x8*)(aoh + go) = oh;
        *(bf16x8*)(aol + go) = ol;
    }
    asm volatile("s_waitcnt lgkmcnt(0)" ::: "memory");
    __builtin_amdgcn_sched_barrier(0);
    #pragma unroll
    for (int f2 = 0; f2 < 4; f2++) {
        u16 hb4[4], lb4[4];
        #pragma unroll
        for (int r = 0; r < 4; r++) {
            const float f = ofB[f2][r] * invB;
            const __bf16 hbv = (__bf16)f;
            hb4[r] = f2bf(f);
            lb4[r] = f2bf(f - (float)hbv);
        }
        u32* pwh = (u32*)&plwH[lr*72 + f2*16 + lg*4];
        u32* pwl = (u32*)&plwL[lr*72 + f2*16 + lg*4];
        pwh[0] = (u32)hb4[0] | ((u32)hb4[1] << 16);
        pwh[1] = (u32)hb4[2] | ((u32)hb4[3] << 16);
        pwl[0] = (u32)lb4[0] | ((u32)lb4[1] << 16);
        pwl[1] = (u32)lb4[2] | ((u32)lb4[3] << 16);
    }
    asm volatile("s_waitcnt lgkmcnt(0)" ::: "memory");
    __builtin_amdgcn_sched_barrier(0);
    #pragma unroll
    for (int pass = 0; pass < 2; pass++) {
        const int qlr = pass*8 + (lane >> 3);
        const int ch = (lane & 7) * 8;
        const bf16x8 oh = *(const bf16x8*)&plwH[qlr*72 + ch];
        const bf16x8 ol = *(const bf16x8*)&plwL[qlr*72 + ch];
        const size_t go = (size_t)(b*TSEQ + wq0B + qlr) * DEMB + h*64 + ch;
        *(bf16x8*)(aoh + go) = oh;
        *(bf16x8*)(aol + go) = ol;
    }
}

// ---------------- MoE routing: fp32 matvec + top-2, NO atomics ----------------
// also emits h = rmsnorm(out) in bf16 (vectorized 16B stores)
__global__ __launch_bounds__(256) void router_k(const float* __restrict__ xout,
                                                const float* __restrict__ rw,
                                                bf16_t* __restrict__ h,
                                                int* __restrict__ idx,
                                                float* __restrict__ wts) {
    const int tok = blockIdx.x * 4 + (threadIdx.x >> 6);
    const int lane = threadIdx.x & 63;
    const float* xr = xout + (size_t)tok * DEMB + lane*16;
    float xv[16];
    float ss = 0.f;
    float acc[NEXP];
    #pragma unroll
    for (int e = 0; e < NEXP; e++) acc[e] = 0.f;
    #pragma unroll
    for (int i = 0; i < 16; i++) {
        xv[i] = xr[i];
        ss += xv[i]*xv[i];
        #pragma unroll
        for (int e = 0; e < NEXP; e++) acc[e] += xv[i] * rw[(lane*16 + i)*NEXP + e];
    }
    #pragma unroll
    for (int off = 32; off; off >>= 1) ss += __shfl_xor(ss, off);
    #pragma unroll
    for (int e = 0; e < NEXP; e++) {
        #pragma unroll
        for (int off = 32; off; off >>= 1) acc[e] += __shfl_xor(acc[e], off);
    }
    const float r = rsqrtf(ss * (1.0f/DEMB) + 1e-5f);
    bf16x8 o0, o1;
    #pragma unroll
    for (int j = 0; j < 8; j++) {
        o0[j] = (__bf16)(xv[j] * r);
        o1[j] = (__bf16)(xv[8+j] * r);
    }
    *(bf16x8*)(h + (size_t)tok*DEMB + lane*16)     = o0;
    *(bf16x8*)(h + (size_t)tok*DEMB + lane*16 + 8) = o1;
    if (lane == 0) {
        float v[NEXP];
        #pragma unroll
        for (int e = 0; e < NEXP; e++) v[e] = acc[e] * r;
        int b0 = 0; float v0 = v[0];
        #pragma unroll
        for (int e = 1; e < NEXP; e++) if (v[e] > v0) { v0 = v[e]; b0 = e; }
        int b1 = -1; float v1 = -1e30f;
        #pragma unroll
        for (int e = 0; e < NEXP; e++) if (e != b0 && v[e] > v1) { v1 = v[e]; b1 = e; }
        const float w0 = 1.f / (1.f + __expf(v1 - v0));
        idx[tok*2+0] = b0; idx[tok*2+1] = b1;
        wts[tok*2+0] = w0; wts[tok*2+1] = 1.f - w0;
    }
}

// ---------------- schedule: counts/offs/rowmap/rowpos via block-wide scan (1 block) ---
// 256 threads; thread t owns slots [t*32, t*32+32). Deterministic, zero global atomics.
__global__ __launch_bounds__(256) void sched_k(const int* __restrict__ idx,
                                               int* __restrict__ counts,
                                               int* __restrict__ offs,
                                               int* __restrict__ rowmap,
                                               int* __restrict__ rowpos) {
    __shared__ int bufA[NEXP][256];
    __shared__ int bufB[NEXP][256];
    __shared__ int runb[256][NEXP];
    __shared__ int offv[NEXP];
    const int t = threadIdx.x;
    int myidx[32];
    #pragma unroll
    for (int i = 0; i < 32; i++) myidx[i] = idx[t*32 + i];
    #pragma unroll
    for (int e = 0; e < NEXP; e++) runb[t][e] = 0;
    #pragma unroll
    for (int i = 0; i < 32; i++) runb[t][myidx[i]]++;
    #pragma unroll
    for (int e = 0; e < NEXP; e++) bufA[e][t] = runb[t][e];
    __syncthreads();
    // Hillis-Steele inclusive scan along t, ping-pong buffers
    int (*cur)[256] = bufA;
    int (*nxt)[256] = bufB;
    for (int d = 1; d < 256; d <<= 1) {
        #pragma unroll
        for (int e = 0; e < NEXP; e++) {
            int v = cur[e][t];
            if (t >= d) v += cur[e][t - d];
            nxt[e][t] = v;
        }
        __syncthreads();
        int (*tmp)[256] = cur; cur = nxt; nxt = tmp;
    }
    if (t == 0) {
        int s = 0;
        #pragma unroll
        for (int e = 0; e < NEXP; e++) {
            const int c = cur[e][255];
            counts[e] = c;
            offs[e] = s;
            offv[e] = s;
            s += c;
        }
    }
    __syncthreads();
    #pragma unroll
    for (int e = 0; e < NEXP; e++) {
        const int excl = (t == 0) ? 0 : cur[e][t-1];
        runb[t][e] = offv[e] + excl;
    }
    #pragma unroll
    for (int i = 0; i < 32; i++) {
        const int e = myidx[i];
        const int r = runb[t][e]++;
        rowmap[r] = (t*32 + i) >> 1;
        rowpos[t*32 + i] = r;
    }
}

__global__ __launch_bounds__(256) void combine_k(const bf16_t* __restrict__ oe,
                                                 const int* __restrict__ rowpos,
                                                 const float* __restrict__ wts,
                                                 float* __restrict__ out) {
    const int n = blockIdx.x;
    const int r0 = rowpos[n*2+0], r1 = rowpos[n*2+1];
    const float w0 = wts[n*2+0], w1 = wts[n*2+1];
    const int c = threadIdx.x * 4;
    const bf16x4 a  = *(const bf16x4*)(oe + (size_t)r0*DEMB + c);
    const bf16x4 b4 = *(const bf16x4*)(oe + (size_t)r1*DEMB + c);
    float4* op = (float4*)(out + (size_t)n*DEMB + c);
    float4 o = *op;
    o.x += w0*(float)a[0] + w1*(float)b4[0];
    o.y += w0*(float)a[1] + w1*(float)b4[1];
    o.z += w0*(float)a[2] + w1*(float)b4[2];
    o.w += w0*(float)a[3] + w1*(float)b4[3];
    *op = o;
}

extern "C" void kernel_launch(void* const* d_in, const int* in_sizes, int n_in,
                              void* d_out, int out_size, void* d_ws, size_t ws_size,
                              hipStream_t stream) {
    (void)in_sizes; (void)n_in; (void)out_size; (void)ws_size;
    const float* x   = (const float*)d_in[0];
    const float* wq  = (const float*)d_in[1];
    const float* wk  = (const float*)d_in[2];
    const float* wv  = (const float*)d_in[3];
    const float* wo  = (const float*)d_in[4];
    const float* rw  = (const float*)d_in[5];
    const float* fc1 = (const float*)d_in[6];
    const float* fc2 = (const float*)d_in[7];
    float* out = (float*)d_out;
    char* ws = (char*)d_ws;
    const size_t MB = 1024*1024;

    bf16_t* wqkv_h = (bf16_t*)(ws);
    bf16_t* wqkv_l = (bf16_t*)(ws + 6*MB);
    bf16_t* wo_h   = (bf16_t*)(ws + 12*MB);
    bf16_t* wo_l   = (bf16_t*)(ws + 14*MB);
    bf16_t* qk_h   = (bf16_t*)(ws + 16*MB);
    bf16_t* qk_l   = (bf16_t*)(ws + 32*MB);
    bf16_t* vt_h   = (bf16_t*)(ws + 48*MB);
    bf16_t* vt_l   = (bf16_t*)(ws + 56*MB);
    bf16_t* fc1_t  = (bf16_t*)(ws + 16*MB);
    bf16_t* fc2_t  = (bf16_t*)(ws + 48*MB);
    bf16_t* h_hi   = (bf16_t*)(ws + 64*MB);
    bf16_t* h_lo   = (bf16_t*)(ws + 72*MB);
    bf16_t* ao_h   = (bf16_t*)(ws + 64*MB);
    bf16_t* ao_l   = (bf16_t*)(ws + 72*MB);
    bf16_t* h      = (bf16_t*)(ws + 80*MB);
    bf16_t* h1     = (bf16_t*)(ws + 88*MB);
    bf16_t* oe     = (bf16_t*)(ws);
    char* meta = ws + 120*MB;
    int*   idx    = (int*)(meta);
    int*   rowmap = (int*)(meta + 128*1024);
    int*   rowpos = (int*)(meta + 192*1024);
    float* wts    = (float*)(meta + 256*1024);
    int*   counts = (int*)(meta + 320*1024);
    int*   offs   = (int*)(meta + 320*1024 + 256);

    const dim3 blk(256);

    // ---- attention path ----
    transp_split_k<<<dim3(32,32), blk, 0, stream>>>(wq, wqkv_h,               wqkv_l,               1024, 1024);
    transp_split_k<<<dim3(32,32), blk, 0, stream>>>(wk, wqkv_h + 1024*1024,   wqkv_l + 1024*1024,   1024, 1024);
    transp_split_k<<<dim3(32,32), blk, 0, stream>>>(wv, wqkv_h + 2*1024*1024, wqkv_l + 2*1024*1024, 1024, 1024);
    transp_split_k<<<dim3(32,32), blk, 0, stream>>>(wo, wo_h,                 wo_l,                 1024, 1024);
    rmsnorm_split_k<<<NTOK, blk, 0, stream>>>(x, h_hi, h_lo);
    gemm_qkv256<<<dim3(12, 16), dim3(512), 0, stream>>>(
        h_hi, h_lo, wqkv_h, wqkv_l, qk_h, qk_l, vt_h, vt_l);
    attn_mfma<<<dim3(16, 16, 2), blk, 0, stream>>>(qk_h, qk_l, vt_h, vt_l, ao_h, ao_l);
    gemm_split<1><<<dim3(DEMB/128, NTOK/128), blk, 0, stream>>>(
        ao_h, ao_l, wo_h, wo_l, x, out, DEMB, 1024);

    // ---- MoE path (fp32 router + rmsnorm fold, atomic-free scheduling, bf16 experts) --
    transp_k<<<dim3(64,32,8), blk, 0, stream>>>(fc1, fc1_t, 1024, 2048);
    transp_k<<<dim3(32,64,8), blk, 0, stream>>>(fc2, fc2_t, 2048, 1024);
    router_k<<<NTOK/4, blk, 0, stream>>>(out, rw, h, idx, wts);
    sched_k<<<1, blk, 0, stream>>>(idx, counts, offs, rowmap, rowpos);
    gemm_moe<2,1><<<dim3(EDIM/128, 32, NEXP), blk, 0, stream>>>(
        h, fc1_t, h1, rowmap, counts, offs, EDIM, 1024);
    gemm_moe<3,0><<<dim3(DEMB/128, 32, NEXP), blk, 0, stream>>>(
        h1, fc2_t, oe, rowmap, counts, offs, DEMB, EDIM);
    combine_k<<<NTOK, blk, 0, stream>>>(oe, rowpos, wts, out);
}